// Round 19
// baseline (66.524 us; speedup 1.0000x reference)
//
#include <hip/hip_runtime.h>

// DR splitting solver. BATCH=4096, N=96, M=48. prox_g1 affine: y = P x + Bmat p.
//   S=(I+Q)^{-1}; T=S Jx^T; K2=Jx T+diag(0,I32); R2=K2^{-1}[T^T|E];
//   P=diag(S,I)-[T;E^T]R2; Bmat=[-P[:,:64] | R2^T]
// Iterate 10x: y=Px+c; x += clamp(2y-x,l,u)-y; out=y[:64].
//
// Round-18 lessons: iter's xo-in-registers worked (iter ~15us); prep1 (~37us)
// is GJ-step LDS-issue + latency bound (16 ld4/thread/step, own-tile RAW).
// Round-19: (a) GJ own tile kept in REGISTERS across steps (reads 16->12 ld4,
// no own-tile latency, in-place update); (b) iter EB=8 / grid 512 -> 2 blocks
// per CU so barrier+dep stalls of one block hide under the other (MFMA cols
// 8..15 zero-padded; MFMA is not the bottleneck).

typedef __attribute__((ext_vector_type(8))) short short8v;
typedef __attribute__((ext_vector_type(4))) short short4v;
typedef __attribute__((ext_vector_type(4))) float float4v;

#define MFMA_BF16 __builtin_amdgcn_mfma_f32_16x16x32_bf16

__device__ __forceinline__ void ld4(const float* p, float* d) {
  float4 v = *(const float4*)p;
  d[0] = v.x; d[1] = v.y; d[2] = v.z; d[3] = v.w;
}
__device__ __forceinline__ void st4(float* p, const float* s) {
  *(float4*)p = make_float4(s[0], s[1], s[2], s[3]);
}
__device__ __forceinline__ float fastrcp(float x) {
  float r = __builtin_amdgcn_rcpf(x);
  return r * (2.0f - x * r);
}
__device__ __forceinline__ void mm4(float W[4][4], const float A[4][4], const float B[4][4]) {
  #pragma unroll
  for (int r = 0; r < 4; ++r)
    #pragma unroll
    for (int q = 0; q < 4; ++q) {
      float s = A[r][0]*B[0][q];
      #pragma unroll
      for (int k = 1; k < 4; ++k) s += A[r][k]*B[k][q];
      W[r][q] = s;
    }
}
__device__ __forceinline__ void inv4(float D[4][4]) {
  #pragma unroll
  for (int p = 0; p < 4; ++p) {
    float pi = fastrcp(D[p][p]);
    D[p][p] = pi;
    #pragma unroll
    for (int q = 0; q < 4; ++q) if (q != p) D[p][q] *= pi;
    #pragma unroll
    for (int i = 0; i < 4; ++i) if (i != p) {
      float f = D[i][p];
      #pragma unroll
      for (int q = 0; q < 4; ++q) if (q != p) D[i][q] -= f * D[p][q];
      D[i][p] = -f * pi;
    }
  }
}
__device__ __forceinline__ unsigned short bf16h_rne(float v) {
  unsigned u = __float_as_uint(v);
  unsigned r = u + 0x7FFFu + ((u >> 16) & 1u);
  return (unsigned short)(r >> 16);
}
__device__ __forceinline__ float bf16_back(unsigned short h) {
  return __uint_as_float(((unsigned)h) << 16);
}
__device__ __forceinline__ void split8(const float v[8], short8v &hi, short8v &lo) {
  #pragma unroll
  for (int j = 0; j < 8; ++j) {
    unsigned short h = bf16h_rne(v[j]);
    hi[j] = (short)h;
    lo[j] = (short)bf16h_rne(v[j] - bf16_back(h));
  }
}

// GJ step with own tile T4 in registers. Reads D,C,R from src; updates T4 in
// place; publishes T4 to dst; 1 barrier.
__device__ __forceinline__ void gj_step64r(const float* __restrict__ src,
                                           float* __restrict__ dst,
                                           int b, int ig, int jg,
                                           float T4[4][4]) {
  float D[4][4], C[4][4], R[4][4];
  #pragma unroll
  for (int r = 0; r < 4; ++r) {
    ld4(&src[(4*b + r)*68 + 4*b],   D[r]);
    ld4(&src[(4*ig + r)*68 + 4*b],  C[r]);
    ld4(&src[(4*b + r)*68 + 4*jg],  R[r]);
  }
  inv4(D);
  if (ig == b) {
    if (jg == b) {
      #pragma unroll
      for (int r = 0; r < 4; ++r)
        #pragma unroll
        for (int q = 0; q < 4; ++q) T4[r][q] = D[r][q];
    } else {
      mm4(T4, D, R);
    }
  } else {
    float E[4][4];
    mm4(E, C, D);
    if (jg == b) {
      #pragma unroll
      for (int r = 0; r < 4; ++r)
        #pragma unroll
        for (int q = 0; q < 4; ++q) T4[r][q] = -E[r][q];
    } else {
      #pragma unroll
      for (int r = 0; r < 4; ++r)
        #pragma unroll
        for (int q = 0; q < 4; ++q) {
          float s = T4[r][q];
          #pragma unroll
          for (int k = 0; k < 4; ++k) s -= E[r][k] * R[k][q];
          T4[r][q] = s;
        }
    }
  }
  #pragma unroll
  for (int r = 0; r < 4; ++r) st4(&dst[(4*ig + r)*68 + 4*jg], T4[r]);
  __syncthreads();
}

__device__ __forceinline__ void gj_step48r(const float* __restrict__ src,
                                           float* __restrict__ dst,
                                           int b, int ig, int jg, bool act,
                                           float T4[4][4]) {
  if (act) {
    float D[4][4], C[4][4], R[4][4];
    #pragma unroll
    for (int r = 0; r < 4; ++r) {
      ld4(&src[(4*b + r)*52 + 4*b],   D[r]);
      ld4(&src[(4*ig + r)*52 + 4*b],  C[r]);
      ld4(&src[(4*b + r)*52 + 4*jg],  R[r]);
    }
    inv4(D);
    if (ig == b) {
      if (jg == b) {
        #pragma unroll
        for (int r = 0; r < 4; ++r)
          #pragma unroll
          for (int q = 0; q < 4; ++q) T4[r][q] = D[r][q];
      } else {
        mm4(T4, D, R);
      }
    } else {
      float E[4][4];
      mm4(E, C, D);
      if (jg == b) {
        #pragma unroll
        for (int r = 0; r < 4; ++r)
          #pragma unroll
          for (int q = 0; q < 4; ++q) T4[r][q] = -E[r][q];
      } else {
        #pragma unroll
        for (int r = 0; r < 4; ++r)
          #pragma unroll
          for (int q = 0; q < 4; ++q) {
            float s = T4[r][q];
            #pragma unroll
            for (int k = 0; k < 4; ++k) s -= E[r][k] * R[k][q];
            T4[r][q] = s;
          }
      }
    }
    #pragma unroll
    for (int r = 0; r < 4; ++r) st4(&dst[(4*ig + r)*52 + 4*jg], T4[r]);
  }
  __syncthreads();
}

// ---------------------------------------------------------------- prep1
__global__ __launch_bounds__(256, 1) void prep1_kernel(
    const float* __restrict__ Qg, const float* __restrict__ Ag,
    const float* __restrict__ Gg,
    float* __restrict__ Sg, float* __restrict__ Tg, float* __restrict__ Kig)
{
  __shared__ float sMa[64*68];   // M1 ping -> S
  __shared__ float sMb[64*68];   // M1 pong -> T (stride 48)
  __shared__ float sK [48*52];   // K2 ping -> Ki
  __shared__ float sJx[48*68];   // Jx staged; also GJ48 pong (48*52)

#define SM_(i,j) sMa[(i)*68+(j)]
#define TT_(i,j) sMb[(i)*48+(j)]
#define SK_(i,j) sK[(i)*52+(j)]
#define JX_(a,k) sJx[(a)*68+(k)]

  const int tid = threadIdx.x;
  const int ig = tid >> 4, jg = tid & 15;

  // stage Jx = [A;G] and M1 = Q + I
  {
    const float4* A4 = (const float4*)Ag;
    const float4* G4 = (const float4*)Gg;
    {
      int a = tid >> 4, kc = tid & 15;
      float v[4]; ld4((const float*)&A4[tid], v);
      st4(&JX_(a, kc*4), v);
    }
    for (int t = tid; t < 512; t += 256) {
      int a = t >> 4, kc = t & 15;
      float v[4]; ld4((const float*)&G4[t], v);
      st4(&JX_(16 + a, kc*4), v);
    }
    const float4* Q4 = (const float4*)Qg;
    for (int t = tid; t < 1024; t += 256) {
      int i = t >> 4, kc = t & 15;
      float v[4]; ld4((const float*)&Q4[t], v);
      st4(&SM_(i, kc*4), v);
    }
  }
  __syncthreads();
  if (tid < 64) SM_(tid, tid) += 1.0f;
  __syncthreads();

  // block-GJ 64, own tile in registers (16 steps, dbuf, 1 barrier/step)
  {
    float T64[4][4];
    #pragma unroll
    for (int r = 0; r < 4; ++r) ld4(&SM_(4*ig + r, 4*jg), T64[r]);
    #pragma unroll 1
    for (int p = 0; p < 8; ++p) {
      gj_step64r(sMa, sMb, 2*p,     ig, jg, T64);
      gj_step64r(sMb, sMa, 2*p + 1, ig, jg, T64);
    }
  }

  // T = S Jx^T : 4x3 register tile/thread
  {
    const int i0 = 4*ig, j0 = 3*jg;
    float acc[4][3] = {};
    #pragma unroll 4
    for (int kq = 0; kq < 16; ++kq) {
      float sv[4][4], jv[3][4];
      ld4(&SM_(i0+0, kq*4), sv[0]); ld4(&SM_(i0+1, kq*4), sv[1]);
      ld4(&SM_(i0+2, kq*4), sv[2]); ld4(&SM_(i0+3, kq*4), sv[3]);
      ld4(&JX_(j0+0, kq*4), jv[0]); ld4(&JX_(j0+1, kq*4), jv[1]);
      ld4(&JX_(j0+2, kq*4), jv[2]);
      #pragma unroll
      for (int r = 0; r < 4; ++r)
        #pragma unroll
        for (int c = 0; c < 3; ++c)
          #pragma unroll
          for (int s = 0; s < 4; ++s)
            acc[r][c] += sv[r][s] * jv[c][s];
    }
    __syncthreads();
    #pragma unroll
    for (int r = 0; r < 4; ++r)
      #pragma unroll
      for (int c = 0; c < 3; ++c)
        TT_(i0+r, j0+c) = acc[r][c];
  }
  __syncthreads();

  // K2 = Jx T + diag(0,I32)  (192 threads, 3x4 tiles)
  if (tid < 192) {
    int ag = tid / 12, bg = tid - ag*12;
    int a0 = ag*3, b0 = bg*4;
    float acc[3][4] = {};
    #pragma unroll 4
    for (int k = 0; k < 64; ++k) {
      float4 tb = *(const float4*)&TT_(k,b0);
      #pragma unroll
      for (int r = 0; r < 3; ++r) {
        float jv = JX_(a0 + r, k);
        acc[r][0] += jv*tb.x; acc[r][1] += jv*tb.y;
        acc[r][2] += jv*tb.z; acc[r][3] += jv*tb.w;
      }
    }
    #pragma unroll
    for (int r = 0; r < 3; ++r)
      #pragma unroll
      for (int q = 0; q < 4; ++q) {
        int a = a0 + r, b = b0 + q;
        SK_(a,b) = acc[r][q] + ((a == b && a >= 16) ? 1.0f : 0.0f);
      }
  }
  __syncthreads();

  // block-GJ 48, own tile in registers (12 steps; pong overlays dead Jx)
  {
    float* KP = sJx;   // 48*52 = 2496 <= 48*68
    const bool act = tid < 144;
    const int ig48 = tid / 12, jg48 = tid - (tid / 12) * 12;
    float T48[4][4];
    if (act) {
      #pragma unroll
      for (int r = 0; r < 4; ++r) ld4(&SK_(4*ig48 + r, 4*jg48), T48[r]);
    }
    #pragma unroll 1
    for (int p = 0; p < 6; ++p) {
      gj_step48r(sK, KP, 2*p,     ig48, jg48, act, T48);
      gj_step48r(KP, sK, 2*p + 1, ig48, jg48, act, T48);
    }
  }

  // write S (64x64), T (64x48), Ki (48x48) to ws
  #pragma unroll 1
  for (int t = tid; t < 1024; t += 256) {
    int i = t >> 4, q = t & 15;
    float v[4]; ld4(&SM_(i, q*4), v); st4(&Sg[i*64 + q*4], v);
  }
  #pragma unroll 1
  for (int t = tid; t < 768; t += 256) {
    int i = t / 12, q = t - 12*(t/12);
    float v[4]; ld4(&TT_(i, q*4), v); st4(&Tg[i*48 + q*4], v);
  }
  #pragma unroll 1
  for (int t = tid; t < 576; t += 256) {
    int k = t / 12, q = t - 12*(t/12);
    float v[4]; ld4(&SK_(k, q*4), v); st4(&Kig[k*48 + q*4], v);
  }
#undef SM_
#undef TT_
#undef SK_
#undef JX_
}

// ---------------------------------------------------------------- prep2
__global__ __launch_bounds__(256, 1) void prep2_kernel(
    const float* __restrict__ Sg, const float* __restrict__ Tg,
    const float* __restrict__ Kig,
    float* __restrict__ Pg, float* __restrict__ Bg)
{
  __shared__ float sT [64*48];
  __shared__ float sKi[48*48];
  __shared__ float sR2[48*96];
  __shared__ float sS [24*64];

  const int tid = threadIdx.x;
  const int b   = blockIdx.x;        // rows [24b, 24b+24)
  const int r0b = 24 * b;

  #pragma unroll 1
  for (int t = tid; t < 768; t += 256) {
    float v[4]; ld4(&Tg[t*4], v); st4(&sT[t*4], v);
  }
  #pragma unroll 1
  for (int t = tid; t < 576; t += 256) {
    float v[4]; ld4(&Kig[t*4], v); st4(&sKi[t*4], v);
  }
  #pragma unroll 1
  for (int t = tid; t < 384; t += 256) {
    int ri = t >> 4, q = t & 15;
    if (r0b + ri < 64) {
      float v[4]; ld4(&Sg[(r0b + ri)*64 + q*4], v); st4(&sS[ri*64 + q*4], v);
    }
  }
  __syncthreads();

  #pragma unroll 1
  for (int t = tid; t < 48*64; t += 256) {
    int k = t >> 6, c = t & 63;
    float acc = 0.0f;
    #pragma unroll 4
    for (int m = 0; m < 48; m += 4) {
      float kv[4], tv[4];
      ld4(&sKi[k*48 + m], kv); ld4(&sT[c*48 + m], tv);
      acc += kv[0]*tv[0] + kv[1]*tv[1] + kv[2]*tv[2] + kv[3]*tv[3];
    }
    sR2[k*96 + c] = acc;
  }
  #pragma unroll 1
  for (int t = tid; t < 48*32; t += 256) {
    int k = t >> 5, j = t & 31;
    sR2[k*96 + 64 + j] = sKi[k*48 + 16 + j];
  }
  __syncthreads();

  #pragma unroll 1
  for (int t = tid; t < 24*48; t += 256) {
    int c = r0b + t / 48, k = t - 48*(t/48);
    Bg[c*112 + 64 + k] = sR2[k*96 + c];
  }

  #pragma unroll 1
  for (int task = tid; task < 576; task += 256) {
    int ri = task / 24, jq = task - 24*(task/24);
    int i = r0b + ri, j0 = jq*4;
    if (i < 64) {
      float acc[4];
      #pragma unroll
      for (int q = 0; q < 4; ++q)
        acc[q] = (j0 < 64) ? sS[ri*64 + j0 + q] : 0.0f;
      #pragma unroll 4
      for (int m = 0; m < 48; m += 4) {
        float tv[4], rv[4][4];
        ld4(&sT[i*48 + m], tv);
        ld4(&sR2[(m+0)*96 + j0], rv[0]);
        ld4(&sR2[(m+1)*96 + j0], rv[1]);
        ld4(&sR2[(m+2)*96 + j0], rv[2]);
        ld4(&sR2[(m+3)*96 + j0], rv[3]);
        #pragma unroll
        for (int q = 0; q < 4; ++q)
          #pragma unroll
          for (int s = 0; s < 4; ++s)
            acc[q] -= tv[s] * rv[s][q];
      }
      #pragma unroll
      for (int q = 0; q < 4; ++q) {
        int j = j0 + q;
        Pg[i*96 + j] = acc[q];
        if (j < 64) Bg[i*112 + j] = -acc[q];
      }
    } else {
      int a = i - 64;
      #pragma unroll
      for (int q = 0; q < 4; ++q) {
        int j = j0 + q;
        float v = (i == j ? 1.0f : 0.0f) - sR2[(16 + a)*96 + j];
        Pg[i*96 + j] = v;
        if (j < 64) Bg[i*112 + j] = -v;
      }
    }
  }
}

// ---------------------------------------------------------------- kernel B
#define EB 8   // elements per block; grid = 512 blocks x 384 threads (2/CU)

__global__ __launch_bounds__(384, 3) void iter_kernel(
    const float* __restrict__ xg, const float* __restrict__ pg,
    const float* __restrict__ Pg, const float* __restrict__ Bg,
    float* __restrict__ outg)
{
  // MFMA split-bf16. Wave w owns row-tile 16w. xo in registers (D-layout ==
  // update layout). Only 8 elements/block: MFMA cols 8..15 are zero-padded
  // (MFMA is not the bottleneck; 2 blocks/CU hides barrier+dep stalls).
  __shared__ short sXh[2][16*104], sXl[2][16*104];

  const int tid   = threadIdx.x;    // 0..383
  const int gbase = blockIdx.x * EB;
  const int w     = tid >> 6;
  const int lane  = tid & 63;
  const int e     = lane & 15;
  const int g     = lane >> 4;
  const int row0  = 16 * w;
  const int rbase = row0 + 4*g;

  // zero cols 8..15 of both buffers (one-time)
  for (int t = tid; t < 8*104; t += 384) {
    int e2 = 8 + t / 104, k = t - 104 * (t / 104);
    sXh[0][e2*104 + k] = 0; sXl[0][e2*104 + k] = 0;
    sXh[1][e2*104 + k] = 0; sXl[1][e2*104 + k] = 0;
  }

  // P fragments (A operand), hi/lo, register-resident
  short8v pfh[3], pfl[3];
  #pragma unroll
  for (int kc = 0; kc < 3; ++kc) {
    float v[8];
    const float* src = Pg + (row0 + e)*96 + 32*kc + 8*g;
    ld4(src, v); ld4(src + 4, v + 4);
    split8(v, pfh[kc], pfl[kc]);
  }

  // x state: my 4 values in registers (e<8 only); splits to LDS buffer 0
  float xo[4] = {0.f, 0.f, 0.f, 0.f};
  if (e < 8) {
    ld4(xg + (size_t)(gbase + e)*96 + rbase, xo);
    short4v hv, lv;
    #pragma unroll
    for (int r = 0; r < 4; ++r) {
      unsigned short h = bf16h_rne(xo[r]);
      hv[r] = (short)h;
      lv[r] = (short)bf16h_rne(xo[r] - bf16_back(h));
    }
    *(short4v*)&sXh[0][e*104 + rbase] = hv;
    *(short4v*)&sXl[0][e*104 + rbase] = lv;
  }

  // c = Bmat @ parms via MFMA (global reads; K=112 padded to 128)
  float4v cfrag = {0.f, 0.f, 0.f, 0.f};
  #pragma unroll
  for (int kc = 0; kc < 4; ++kc) {
    const int kbase = 32*kc + 8*g;
    float v[8];
    short8v ah, al, bh, bl;
    if (kbase < 112) {
      const float* src = Bg + (row0 + e)*112 + kbase;
      ld4(src, v); ld4(src + 4, v + 4);
    } else {
      #pragma unroll
      for (int j = 0; j < 8; ++j) v[j] = 0.f;
    }
    split8(v, ah, al);
    if (kbase < 112 && e < 8) {
      const float* src = pg + (size_t)(gbase + e)*112 + kbase;
      ld4(src, v); ld4(src + 4, v + 4);
    } else {
      #pragma unroll
      for (int j = 0; j < 8; ++j) v[j] = 0.f;
    }
    split8(v, bh, bl);
    cfrag = MFMA_BF16(ah, bh, cfrag, 0, 0, 0);
    cfrag = MFMA_BF16(ah, bl, cfrag, 0, 0, 0);
    cfrag = MFMA_BF16(al, bh, cfrag, 0, 0, 0);
  }

  __syncthreads();   // x splits + zero pads visible

  const float lob = (row0 < 64) ? -1000.f : 0.f;
  int cur = 0;

  #pragma unroll 1
  for (int it = 0; it < 10; ++it) {
    const short* xhp = &sXh[cur][0];
    const short* xlp = &sXl[cur][0];
    float4v accs0 = cfrag;
    float4v accs1 = {0.f, 0.f, 0.f, 0.f};
    float4v accs2 = {0.f, 0.f, 0.f, 0.f};
    {
      int off = e*104 + 8*g;
      short8v xh0 = *(const short8v*)&xhp[off];
      short8v xl0 = *(const short8v*)&xlp[off];
      short8v xh1 = *(const short8v*)&xhp[off + 32];
      short8v xl1 = *(const short8v*)&xlp[off + 32];
      short8v xh2 = *(const short8v*)&xhp[off + 64];
      short8v xl2 = *(const short8v*)&xlp[off + 64];
      accs0 = MFMA_BF16(pfh[0], xh0, accs0, 0, 0, 0);
      accs1 = MFMA_BF16(pfh[1], xh1, accs1, 0, 0, 0);
      accs2 = MFMA_BF16(pfh[2], xh2, accs2, 0, 0, 0);
      accs0 = MFMA_BF16(pfh[0], xl0, accs0, 0, 0, 0);
      accs1 = MFMA_BF16(pfh[1], xl1, accs1, 0, 0, 0);
      accs2 = MFMA_BF16(pfh[2], xl2, accs2, 0, 0, 0);
      accs0 = MFMA_BF16(pfl[0], xh0, accs0, 0, 0, 0);
      accs1 = MFMA_BF16(pfl[1], xh1, accs1, 0, 0, 0);
      accs2 = MFMA_BF16(pfl[2], xh2, accs2, 0, 0, 0);
    }
    float4v acc = accs0 + accs1 + accs2;

    if (it < 9) {
      if (e < 8) {
        short4v hv, lv;
        #pragma unroll
        for (int r = 0; r < 4; ++r) {
          float y = acc[r];
          float z = fminf(fmaxf(2.f*y - xo[r], lob), 1000.f);
          float xn = xo[r] + z - y;
          xo[r] = xn;
          unsigned short h = bf16h_rne(xn);
          hv[r] = (short)h;
          lv[r] = (short)bf16h_rne(xn - bf16_back(h));
        }
        *(short4v*)&sXh[cur ^ 1][e*104 + rbase] = hv;
        *(short4v*)&sXl[cur ^ 1][e*104 + rbase] = lv;
      }
      __syncthreads();
      cur ^= 1;
    } else {
      if (row0 < 64 && e < 8) {
        *(float4*)&outg[(gbase + e)*64 + rbase] =
            make_float4(acc[0], acc[1], acc[2], acc[3]);
      }
    }
  }
}

// ---------------------------------------------------------------- launch
extern "C" void kernel_launch(void* const* d_in, const int* in_sizes, int n_in,
                              void* d_out, int out_size, void* d_ws, size_t ws_size,
                              hipStream_t stream) {
  const float* x     = (const float*)d_in[0];   // (4096, 96)
  const float* parms = (const float*)d_in[1];   // (4096, 112)
  const float* Qg    = (const float*)d_in[2];   // (64, 64)
  const float* Ag    = (const float*)d_in[3];   // (16, 64)
  const float* Gg    = (const float*)d_in[4];   // (32, 64)
  float* out = (float*)d_out;                   // (4096, 64)

  float* ws  = (float*)d_ws;
  float* Pg  = ws;                  // 96*96  = 9216
  float* Bg  = ws + 9216;           // 96*112 = 10752
  float* Sg  = ws + 19968;          // 64*64  = 4096
  float* Tg  = ws + 24064;          // 64*48  = 3072
  float* Kig = ws + 27136;          // 48*48  = 2304

  prep1_kernel<<<1, 256, 0, stream>>>(Qg, Ag, Gg, Sg, Tg, Kig);
  prep2_kernel<<<4, 256, 0, stream>>>(Sg, Tg, Kig, Pg, Bg);
  iter_kernel<<<4096 / EB, 384, 0, stream>>>(x, parms, Pg, Bg, out);
}

// Round 20
// 60.435 us; speedup vs baseline: 1.1008x; 1.1008x over previous
//
#include <hip/hip_runtime.h>

// DR splitting solver. BATCH=4096, N=96, M=48. prox_g1 affine: y = P x + Bmat p.
//   S=(I+Q)^{-1}; T=S Jx^T; K2=Jx T+diag(0,I32); R2=K2^{-1}[T^T|E];
//   P=diag(S,I)-[T;E^T]R2; Bmat=[-P[:,:64] | R2^T]
// Iterate 10x: y=Px+c; x += clamp(2y-x,l,u)-y; out=y[:64].
//
// Round-19 lesson: bundled changes; EB=8 iter doubled per-block fixed cost
// (prologue + MFMA) -> +12us. NEVER shrink iter's EB. Round-20 single-variable:
// iter = round-18 exact (EB=16, ~15us proven); prep1 keeps own-tile-in-registers
// GJ (the one change under test vs the 54.4us baseline).

typedef __attribute__((ext_vector_type(8))) short short8v;
typedef __attribute__((ext_vector_type(4))) short short4v;
typedef __attribute__((ext_vector_type(4))) float float4v;

#define MFMA_BF16 __builtin_amdgcn_mfma_f32_16x16x32_bf16

__device__ __forceinline__ void ld4(const float* p, float* d) {
  float4 v = *(const float4*)p;
  d[0] = v.x; d[1] = v.y; d[2] = v.z; d[3] = v.w;
}
__device__ __forceinline__ void st4(float* p, const float* s) {
  *(float4*)p = make_float4(s[0], s[1], s[2], s[3]);
}
__device__ __forceinline__ float fastrcp(float x) {
  float r = __builtin_amdgcn_rcpf(x);
  return r * (2.0f - x * r);
}
__device__ __forceinline__ void mm4(float W[4][4], const float A[4][4], const float B[4][4]) {
  #pragma unroll
  for (int r = 0; r < 4; ++r)
    #pragma unroll
    for (int q = 0; q < 4; ++q) {
      float s = A[r][0]*B[0][q];
      #pragma unroll
      for (int k = 1; k < 4; ++k) s += A[r][k]*B[k][q];
      W[r][q] = s;
    }
}
__device__ __forceinline__ void inv4(float D[4][4]) {
  #pragma unroll
  for (int p = 0; p < 4; ++p) {
    float pi = fastrcp(D[p][p]);
    D[p][p] = pi;
    #pragma unroll
    for (int q = 0; q < 4; ++q) if (q != p) D[p][q] *= pi;
    #pragma unroll
    for (int i = 0; i < 4; ++i) if (i != p) {
      float f = D[i][p];
      #pragma unroll
      for (int q = 0; q < 4; ++q) if (q != p) D[i][q] -= f * D[p][q];
      D[i][p] = -f * pi;
    }
  }
}
__device__ __forceinline__ unsigned short bf16h_rne(float v) {
  unsigned u = __float_as_uint(v);
  unsigned r = u + 0x7FFFu + ((u >> 16) & 1u);
  return (unsigned short)(r >> 16);
}
__device__ __forceinline__ float bf16_back(unsigned short h) {
  return __uint_as_float(((unsigned)h) << 16);
}
__device__ __forceinline__ void split8(const float v[8], short8v &hi, short8v &lo) {
  #pragma unroll
  for (int j = 0; j < 8; ++j) {
    unsigned short h = bf16h_rne(v[j]);
    hi[j] = (short)h;
    lo[j] = (short)bf16h_rne(v[j] - bf16_back(h));
  }
}

// GJ step with own tile T4 in registers. Reads D,C,R from src; updates T4 in
// place; publishes T4 to dst; 1 barrier.
__device__ __forceinline__ void gj_step64r(const float* __restrict__ src,
                                           float* __restrict__ dst,
                                           int b, int ig, int jg,
                                           float T4[4][4]) {
  float D[4][4], C[4][4], R[4][4];
  #pragma unroll
  for (int r = 0; r < 4; ++r) {
    ld4(&src[(4*b + r)*68 + 4*b],   D[r]);
    ld4(&src[(4*ig + r)*68 + 4*b],  C[r]);
    ld4(&src[(4*b + r)*68 + 4*jg],  R[r]);
  }
  inv4(D);
  if (ig == b) {
    if (jg == b) {
      #pragma unroll
      for (int r = 0; r < 4; ++r)
        #pragma unroll
        for (int q = 0; q < 4; ++q) T4[r][q] = D[r][q];
    } else {
      mm4(T4, D, R);
    }
  } else {
    float E[4][4];
    mm4(E, C, D);
    if (jg == b) {
      #pragma unroll
      for (int r = 0; r < 4; ++r)
        #pragma unroll
        for (int q = 0; q < 4; ++q) T4[r][q] = -E[r][q];
    } else {
      #pragma unroll
      for (int r = 0; r < 4; ++r)
        #pragma unroll
        for (int q = 0; q < 4; ++q) {
          float s = T4[r][q];
          #pragma unroll
          for (int k = 0; k < 4; ++k) s -= E[r][k] * R[k][q];
          T4[r][q] = s;
        }
    }
  }
  #pragma unroll
  for (int r = 0; r < 4; ++r) st4(&dst[(4*ig + r)*68 + 4*jg], T4[r]);
  __syncthreads();
}

__device__ __forceinline__ void gj_step48r(const float* __restrict__ src,
                                           float* __restrict__ dst,
                                           int b, int ig, int jg, bool act,
                                           float T4[4][4]) {
  if (act) {
    float D[4][4], C[4][4], R[4][4];
    #pragma unroll
    for (int r = 0; r < 4; ++r) {
      ld4(&src[(4*b + r)*52 + 4*b],   D[r]);
      ld4(&src[(4*ig + r)*52 + 4*b],  C[r]);
      ld4(&src[(4*b + r)*52 + 4*jg],  R[r]);
    }
    inv4(D);
    if (ig == b) {
      if (jg == b) {
        #pragma unroll
        for (int r = 0; r < 4; ++r)
          #pragma unroll
          for (int q = 0; q < 4; ++q) T4[r][q] = D[r][q];
      } else {
        mm4(T4, D, R);
      }
    } else {
      float E[4][4];
      mm4(E, C, D);
      if (jg == b) {
        #pragma unroll
        for (int r = 0; r < 4; ++r)
          #pragma unroll
          for (int q = 0; q < 4; ++q) T4[r][q] = -E[r][q];
      } else {
        #pragma unroll
        for (int r = 0; r < 4; ++r)
          #pragma unroll
          for (int q = 0; q < 4; ++q) {
            float s = T4[r][q];
            #pragma unroll
            for (int k = 0; k < 4; ++k) s -= E[r][k] * R[k][q];
            T4[r][q] = s;
          }
      }
    }
    #pragma unroll
    for (int r = 0; r < 4; ++r) st4(&dst[(4*ig + r)*52 + 4*jg], T4[r]);
  }
  __syncthreads();
}

// ---------------------------------------------------------------- prep1
__global__ __launch_bounds__(256, 1) void prep1_kernel(
    const float* __restrict__ Qg, const float* __restrict__ Ag,
    const float* __restrict__ Gg,
    float* __restrict__ Sg, float* __restrict__ Tg, float* __restrict__ Kig)
{
  __shared__ float sMa[64*68];   // M1 ping -> S
  __shared__ float sMb[64*68];   // M1 pong -> T (stride 48)
  __shared__ float sK [48*52];   // K2 ping -> Ki
  __shared__ float sJx[48*68];   // Jx staged; also GJ48 pong (48*52)

#define SM_(i,j) sMa[(i)*68+(j)]
#define TT_(i,j) sMb[(i)*48+(j)]
#define SK_(i,j) sK[(i)*52+(j)]
#define JX_(a,k) sJx[(a)*68+(k)]

  const int tid = threadIdx.x;
  const int ig = tid >> 4, jg = tid & 15;

  // stage Jx = [A;G] and M1 = Q + I
  {
    const float4* A4 = (const float4*)Ag;
    const float4* G4 = (const float4*)Gg;
    {
      int a = tid >> 4, kc = tid & 15;
      float v[4]; ld4((const float*)&A4[tid], v);
      st4(&JX_(a, kc*4), v);
    }
    for (int t = tid; t < 512; t += 256) {
      int a = t >> 4, kc = t & 15;
      float v[4]; ld4((const float*)&G4[t], v);
      st4(&JX_(16 + a, kc*4), v);
    }
    const float4* Q4 = (const float4*)Qg;
    for (int t = tid; t < 1024; t += 256) {
      int i = t >> 4, kc = t & 15;
      float v[4]; ld4((const float*)&Q4[t], v);
      st4(&SM_(i, kc*4), v);
    }
  }
  __syncthreads();
  if (tid < 64) SM_(tid, tid) += 1.0f;
  __syncthreads();

  // block-GJ 64, own tile in registers (16 steps, dbuf, 1 barrier/step)
  {
    float T64[4][4];
    #pragma unroll
    for (int r = 0; r < 4; ++r) ld4(&SM_(4*ig + r, 4*jg), T64[r]);
    #pragma unroll 1
    for (int p = 0; p < 8; ++p) {
      gj_step64r(sMa, sMb, 2*p,     ig, jg, T64);
      gj_step64r(sMb, sMa, 2*p + 1, ig, jg, T64);
    }
  }

  // T = S Jx^T : 4x3 register tile/thread
  {
    const int i0 = 4*ig, j0 = 3*jg;
    float acc[4][3] = {};
    #pragma unroll 4
    for (int kq = 0; kq < 16; ++kq) {
      float sv[4][4], jv[3][4];
      ld4(&SM_(i0+0, kq*4), sv[0]); ld4(&SM_(i0+1, kq*4), sv[1]);
      ld4(&SM_(i0+2, kq*4), sv[2]); ld4(&SM_(i0+3, kq*4), sv[3]);
      ld4(&JX_(j0+0, kq*4), jv[0]); ld4(&JX_(j0+1, kq*4), jv[1]);
      ld4(&JX_(j0+2, kq*4), jv[2]);
      #pragma unroll
      for (int r = 0; r < 4; ++r)
        #pragma unroll
        for (int c = 0; c < 3; ++c)
          #pragma unroll
          for (int s = 0; s < 4; ++s)
            acc[r][c] += sv[r][s] * jv[c][s];
    }
    __syncthreads();
    #pragma unroll
    for (int r = 0; r < 4; ++r)
      #pragma unroll
      for (int c = 0; c < 3; ++c)
        TT_(i0+r, j0+c) = acc[r][c];
  }
  __syncthreads();

  // K2 = Jx T + diag(0,I32)  (192 threads, 3x4 tiles)
  if (tid < 192) {
    int ag = tid / 12, bg = tid - ag*12;
    int a0 = ag*3, b0 = bg*4;
    float acc[3][4] = {};
    #pragma unroll 4
    for (int k = 0; k < 64; ++k) {
      float4 tb = *(const float4*)&TT_(k,b0);
      #pragma unroll
      for (int r = 0; r < 3; ++r) {
        float jv = JX_(a0 + r, k);
        acc[r][0] += jv*tb.x; acc[r][1] += jv*tb.y;
        acc[r][2] += jv*tb.z; acc[r][3] += jv*tb.w;
      }
    }
    #pragma unroll
    for (int r = 0; r < 3; ++r)
      #pragma unroll
      for (int q = 0; q < 4; ++q) {
        int a = a0 + r, b = b0 + q;
        SK_(a,b) = acc[r][q] + ((a == b && a >= 16) ? 1.0f : 0.0f);
      }
  }
  __syncthreads();

  // block-GJ 48, own tile in registers (12 steps; pong overlays dead Jx)
  {
    float* KP = sJx;   // 48*52 = 2496 <= 48*68
    const bool act = tid < 144;
    const int ig48 = tid / 12, jg48 = tid - (tid / 12) * 12;
    float T48[4][4];
    if (act) {
      #pragma unroll
      for (int r = 0; r < 4; ++r) ld4(&SK_(4*ig48 + r, 4*jg48), T48[r]);
    }
    #pragma unroll 1
    for (int p = 0; p < 6; ++p) {
      gj_step48r(sK, KP, 2*p,     ig48, jg48, act, T48);
      gj_step48r(KP, sK, 2*p + 1, ig48, jg48, act, T48);
    }
  }

  // write S (64x64), T (64x48), Ki (48x48) to ws
  #pragma unroll 1
  for (int t = tid; t < 1024; t += 256) {
    int i = t >> 4, q = t & 15;
    float v[4]; ld4(&SM_(i, q*4), v); st4(&Sg[i*64 + q*4], v);
  }
  #pragma unroll 1
  for (int t = tid; t < 768; t += 256) {
    int i = t / 12, q = t - 12*(t/12);
    float v[4]; ld4(&TT_(i, q*4), v); st4(&Tg[i*48 + q*4], v);
  }
  #pragma unroll 1
  for (int t = tid; t < 576; t += 256) {
    int k = t / 12, q = t - 12*(t/12);
    float v[4]; ld4(&SK_(k, q*4), v); st4(&Kig[k*48 + q*4], v);
  }
#undef SM_
#undef TT_
#undef SK_
#undef JX_
}

// ---------------------------------------------------------------- prep2
__global__ __launch_bounds__(256, 1) void prep2_kernel(
    const float* __restrict__ Sg, const float* __restrict__ Tg,
    const float* __restrict__ Kig,
    float* __restrict__ Pg, float* __restrict__ Bg)
{
  __shared__ float sT [64*48];
  __shared__ float sKi[48*48];
  __shared__ float sR2[48*96];
  __shared__ float sS [24*64];

  const int tid = threadIdx.x;
  const int b   = blockIdx.x;        // rows [24b, 24b+24)
  const int r0b = 24 * b;

  #pragma unroll 1
  for (int t = tid; t < 768; t += 256) {
    float v[4]; ld4(&Tg[t*4], v); st4(&sT[t*4], v);
  }
  #pragma unroll 1
  for (int t = tid; t < 576; t += 256) {
    float v[4]; ld4(&Kig[t*4], v); st4(&sKi[t*4], v);
  }
  #pragma unroll 1
  for (int t = tid; t < 384; t += 256) {
    int ri = t >> 4, q = t & 15;
    if (r0b + ri < 64) {
      float v[4]; ld4(&Sg[(r0b + ri)*64 + q*4], v); st4(&sS[ri*64 + q*4], v);
    }
  }
  __syncthreads();

  #pragma unroll 1
  for (int t = tid; t < 48*64; t += 256) {
    int k = t >> 6, c = t & 63;
    float acc = 0.0f;
    #pragma unroll 4
    for (int m = 0; m < 48; m += 4) {
      float kv[4], tv[4];
      ld4(&sKi[k*48 + m], kv); ld4(&sT[c*48 + m], tv);
      acc += kv[0]*tv[0] + kv[1]*tv[1] + kv[2]*tv[2] + kv[3]*tv[3];
    }
    sR2[k*96 + c] = acc;
  }
  #pragma unroll 1
  for (int t = tid; t < 48*32; t += 256) {
    int k = t >> 5, j = t & 31;
    sR2[k*96 + 64 + j] = sKi[k*48 + 16 + j];
  }
  __syncthreads();

  #pragma unroll 1
  for (int t = tid; t < 24*48; t += 256) {
    int c = r0b + t / 48, k = t - 48*(t/48);
    Bg[c*112 + 64 + k] = sR2[k*96 + c];
  }

  #pragma unroll 1
  for (int task = tid; task < 576; task += 256) {
    int ri = task / 24, jq = task - 24*(task/24);
    int i = r0b + ri, j0 = jq*4;
    if (i < 64) {
      float acc[4];
      #pragma unroll
      for (int q = 0; q < 4; ++q)
        acc[q] = (j0 < 64) ? sS[ri*64 + j0 + q] : 0.0f;
      #pragma unroll 4
      for (int m = 0; m < 48; m += 4) {
        float tv[4], rv[4][4];
        ld4(&sT[i*48 + m], tv);
        ld4(&sR2[(m+0)*96 + j0], rv[0]);
        ld4(&sR2[(m+1)*96 + j0], rv[1]);
        ld4(&sR2[(m+2)*96 + j0], rv[2]);
        ld4(&sR2[(m+3)*96 + j0], rv[3]);
        #pragma unroll
        for (int q = 0; q < 4; ++q)
          #pragma unroll
          for (int s = 0; s < 4; ++s)
            acc[q] -= tv[s] * rv[s][q];
      }
      #pragma unroll
      for (int q = 0; q < 4; ++q) {
        int j = j0 + q;
        Pg[i*96 + j] = acc[q];
        if (j < 64) Bg[i*112 + j] = -acc[q];
      }
    } else {
      int a = i - 64;
      #pragma unroll
      for (int q = 0; q < 4; ++q) {
        int j = j0 + q;
        float v = (i == j ? 1.0f : 0.0f) - sR2[(16 + a)*96 + j];
        Pg[i*96 + j] = v;
        if (j < 64) Bg[i*112 + j] = -v;
      }
    }
  }
}

// ---------------------------------------------------------------- kernel B
#define EB 16   // elements per block; grid = 256 blocks x 384 threads

__global__ __launch_bounds__(384, 1) void iter_kernel(
    const float* __restrict__ xg, const float* __restrict__ pg,
    const float* __restrict__ Pg, const float* __restrict__ Bg,
    float* __restrict__ outg)
{
  // MFMA split-bf16. Wave w owns row-tile 16w. xo kept in 4 f32 registers
  // across iterations (D-layout == update layout); LDS holds only the bf16
  // hi/lo splits of x (double-buffered). (round-18 exact)
  __shared__ short sXh[2][EB*104], sXl[2][EB*104];

  const int tid   = threadIdx.x;    // 0..383
  const int gbase = blockIdx.x * EB;
  const int w     = tid >> 6;
  const int lane  = tid & 63;
  const int e     = lane & 15;
  const int g     = lane >> 4;
  const int row0  = 16 * w;
  const int rbase = row0 + 4*g;

  // P fragments (A operand), hi/lo, register-resident
  short8v pfh[3], pfl[3];
  #pragma unroll
  for (int kc = 0; kc < 3; ++kc) {
    float v[8];
    const float* src = Pg + (row0 + e)*96 + 32*kc + 8*g;
    ld4(src, v); ld4(src + 4, v + 4);
    split8(v, pfh[kc], pfl[kc]);
  }

  // x state: my 4 values in registers; splits to LDS buffer 0
  float xo[4];
  ld4(xg + (size_t)(gbase + e)*96 + rbase, xo);
  {
    short4v hv, lv;
    #pragma unroll
    for (int r = 0; r < 4; ++r) {
      unsigned short h = bf16h_rne(xo[r]);
      hv[r] = (short)h;
      lv[r] = (short)bf16h_rne(xo[r] - bf16_back(h));
    }
    *(short4v*)&sXh[0][e*104 + rbase] = hv;
    *(short4v*)&sXl[0][e*104 + rbase] = lv;
  }

  // c = Bmat @ parms via MFMA (global reads; K=112 padded to 128)
  float4v cfrag = {0.f, 0.f, 0.f, 0.f};
  #pragma unroll
  for (int kc = 0; kc < 4; ++kc) {
    const int kbase = 32*kc + 8*g;
    float v[8];
    short8v ah, al, bh, bl;
    if (kbase < 112) {
      const float* src = Bg + (row0 + e)*112 + kbase;
      ld4(src, v); ld4(src + 4, v + 4);
    } else {
      #pragma unroll
      for (int j = 0; j < 8; ++j) v[j] = 0.f;
    }
    split8(v, ah, al);
    if (kbase < 112) {
      const float* src = pg + (size_t)(gbase + e)*112 + kbase;
      ld4(src, v); ld4(src + 4, v + 4);
    } else {
      #pragma unroll
      for (int j = 0; j < 8; ++j) v[j] = 0.f;
    }
    split8(v, bh, bl);
    cfrag = MFMA_BF16(ah, bh, cfrag, 0, 0, 0);
    cfrag = MFMA_BF16(ah, bl, cfrag, 0, 0, 0);
    cfrag = MFMA_BF16(al, bh, cfrag, 0, 0, 0);
  }

  __syncthreads();   // x splits visible

  const float lob = (row0 < 64) ? -1000.f : 0.f;
  int cur = 0;

  #pragma unroll 1
  for (int it = 0; it < 10; ++it) {
    const short* xhp = &sXh[cur][0];
    const short* xlp = &sXl[cur][0];
    float4v accs0 = cfrag;
    float4v accs1 = {0.f, 0.f, 0.f, 0.f};
    float4v accs2 = {0.f, 0.f, 0.f, 0.f};
    {
      int off = e*104 + 8*g;
      short8v xh0 = *(const short8v*)&xhp[off];
      short8v xl0 = *(const short8v*)&xlp[off];
      short8v xh1 = *(const short8v*)&xhp[off + 32];
      short8v xl1 = *(const short8v*)&xlp[off + 32];
      short8v xh2 = *(const short8v*)&xhp[off + 64];
      short8v xl2 = *(const short8v*)&xlp[off + 64];
      accs0 = MFMA_BF16(pfh[0], xh0, accs0, 0, 0, 0);
      accs1 = MFMA_BF16(pfh[1], xh1, accs1, 0, 0, 0);
      accs2 = MFMA_BF16(pfh[2], xh2, accs2, 0, 0, 0);
      accs0 = MFMA_BF16(pfh[0], xl0, accs0, 0, 0, 0);
      accs1 = MFMA_BF16(pfh[1], xl1, accs1, 0, 0, 0);
      accs2 = MFMA_BF16(pfh[2], xl2, accs2, 0, 0, 0);
      accs0 = MFMA_BF16(pfl[0], xh0, accs0, 0, 0, 0);
      accs1 = MFMA_BF16(pfl[1], xh1, accs1, 0, 0, 0);
      accs2 = MFMA_BF16(pfl[2], xh2, accs2, 0, 0, 0);
    }
    float4v acc = accs0 + accs1 + accs2;

    if (it < 9) {
      short4v hv, lv;
      #pragma unroll
      for (int r = 0; r < 4; ++r) {
        float y = acc[r];
        float z = fminf(fmaxf(2.f*y - xo[r], lob), 1000.f);
        float xn = xo[r] + z - y;
        xo[r] = xn;
        unsigned short h = bf16h_rne(xn);
        hv[r] = (short)h;
        lv[r] = (short)bf16h_rne(xn - bf16_back(h));
      }
      *(short4v*)&sXh[cur ^ 1][e*104 + rbase] = hv;
      *(short4v*)&sXl[cur ^ 1][e*104 + rbase] = lv;
      __syncthreads();
      cur ^= 1;
    } else {
      if (row0 < 64) {
        *(float4*)&outg[(gbase + e)*64 + rbase] =
            make_float4(acc[0], acc[1], acc[2], acc[3]);
      }
    }
  }
}

// ---------------------------------------------------------------- launch
extern "C" void kernel_launch(void* const* d_in, const int* in_sizes, int n_in,
                              void* d_out, int out_size, void* d_ws, size_t ws_size,
                              hipStream_t stream) {
  const float* x     = (const float*)d_in[0];   // (4096, 96)
  const float* parms = (const float*)d_in[1];   // (4096, 112)
  const float* Qg    = (const float*)d_in[2];   // (64, 64)
  const float* Ag    = (const float*)d_in[3];   // (16, 64)
  const float* Gg    = (const float*)d_in[4];   // (32, 64)
  float* out = (float*)d_out;                   // (4096, 64)

  float* ws  = (float*)d_ws;
  float* Pg  = ws;                  // 96*96  = 9216
  float* Bg  = ws + 9216;           // 96*112 = 10752
  float* Sg  = ws + 19968;          // 64*64  = 4096
  float* Tg  = ws + 24064;          // 64*48  = 3072
  float* Kig = ws + 27136;          // 48*48  = 2304

  prep1_kernel<<<1, 256, 0, stream>>>(Qg, Ag, Gg, Sg, Tg, Kig);
  prep2_kernel<<<4, 256, 0, stream>>>(Sg, Tg, Kig, Pg, Bg);
  iter_kernel<<<4096 / EB, 384, 0, stream>>>(x, parms, Pg, Bg, out);
}

// Round 21
// 55.521 us; speedup vs baseline: 1.1982x; 1.0885x over previous
//
#include <hip/hip_runtime.h>

// DR splitting solver. BATCH=4096, N=96, M=48. prox_g1 affine: y = P x + Bmat p.
//   S=(I+Q)^{-1}; T=S Jx^T; K2=Jx T+diag(0,I32); R2=K2^{-1}[T^T|E];
//   P=diag(S,I)-[T;E^T]R2; Bmat=[-P[:,:64] | R2^T]
// Iterate 10x: y=Px+c; x += clamp(2y-x,l,u)-y; out=y[:64].
//
// Round-20 lesson: own-tile-in-register GJ hurt (+6us; publish-store serialized
// on the register update chain) -> reverted to round-18 LDS-read GJ (proven
// 54.4us). Round-21 single variable: inv4 Gauss-Jordan (4 serial pivots,
// ~280cy chain, on the critical path of all 28 GJ steps) -> closed-form
// COFACTOR inverse (independent 2x2 subdets + 1 rcp, chain ~70cy). Safe:
// pivot blocks are principal blocks of Schur complements of M>=I (det>=1).

typedef __attribute__((ext_vector_type(8))) short short8v;
typedef __attribute__((ext_vector_type(4))) short short4v;
typedef __attribute__((ext_vector_type(4))) float float4v;

#define MFMA_BF16 __builtin_amdgcn_mfma_f32_16x16x32_bf16

__device__ __forceinline__ void ld4(const float* p, float* d) {
  float4 v = *(const float4*)p;
  d[0] = v.x; d[1] = v.y; d[2] = v.z; d[3] = v.w;
}
__device__ __forceinline__ void st4(float* p, const float* s) {
  *(float4*)p = make_float4(s[0], s[1], s[2], s[3]);
}
__device__ __forceinline__ float fastrcp(float x) {
  float r = __builtin_amdgcn_rcpf(x);
  return r * (2.0f - x * r);
}
__device__ __forceinline__ void mm4(float W[4][4], const float A[4][4], const float B[4][4]) {
  #pragma unroll
  for (int r = 0; r < 4; ++r)
    #pragma unroll
    for (int q = 0; q < 4; ++q) {
      float s = A[r][0]*B[0][q];
      #pragma unroll
      for (int k = 1; k < 4; ++k) s += A[r][k]*B[k][q];
      W[r][q] = s;
    }
}
// closed-form 4x4 inverse (cofactor/adjugate): shallow dependency chain.
// Valid without pivoting: D is a principal block of a Schur complement of an
// SPD matrix (det > 0; for M1-path det >= 1).
__device__ __forceinline__ void inv4(float D[4][4]) {
  float s0 = D[0][0]*D[1][1] - D[0][1]*D[1][0];
  float s1 = D[0][0]*D[1][2] - D[0][2]*D[1][0];
  float s2 = D[0][0]*D[1][3] - D[0][3]*D[1][0];
  float s3 = D[0][1]*D[1][2] - D[0][2]*D[1][1];
  float s4 = D[0][1]*D[1][3] - D[0][3]*D[1][1];
  float s5 = D[0][2]*D[1][3] - D[0][3]*D[1][2];
  float c5 = D[2][2]*D[3][3] - D[2][3]*D[3][2];
  float c4 = D[2][1]*D[3][3] - D[2][3]*D[3][1];
  float c3 = D[2][1]*D[3][2] - D[2][2]*D[3][1];
  float c2 = D[2][0]*D[3][3] - D[2][3]*D[3][0];
  float c1 = D[2][0]*D[3][2] - D[2][2]*D[3][0];
  float c0 = D[2][0]*D[3][1] - D[2][1]*D[3][0];
  float det = s0*c5 - s1*c4 + s2*c3 + s3*c2 - s4*c1 + s5*c0;
  float id = fastrcp(det);
  float W[4][4];
  W[0][0] = ( D[1][1]*c5 - D[1][2]*c4 + D[1][3]*c3) * id;
  W[0][1] = (-D[0][1]*c5 + D[0][2]*c4 - D[0][3]*c3) * id;
  W[0][2] = ( D[3][1]*s5 - D[3][2]*s4 + D[3][3]*s3) * id;
  W[0][3] = (-D[2][1]*s5 + D[2][2]*s4 - D[2][3]*s3) * id;
  W[1][0] = (-D[1][0]*c5 + D[1][2]*c2 - D[1][3]*c1) * id;
  W[1][1] = ( D[0][0]*c5 - D[0][2]*c2 + D[0][3]*c1) * id;
  W[1][2] = (-D[3][0]*s5 + D[3][2]*s2 - D[3][3]*s1) * id;
  W[1][3] = ( D[2][0]*s5 - D[2][2]*s2 + D[2][3]*s1) * id;
  W[2][0] = ( D[1][0]*c4 - D[1][1]*c2 + D[1][3]*c0) * id;
  W[2][1] = (-D[0][0]*c4 + D[0][1]*c2 - D[0][3]*c0) * id;
  W[2][2] = ( D[3][0]*s4 - D[3][1]*s2 + D[3][3]*s0) * id;
  W[2][3] = (-D[2][0]*s4 + D[2][1]*s2 - D[2][3]*s0) * id;
  W[3][0] = (-D[1][0]*c3 + D[1][1]*c1 - D[1][2]*c0) * id;
  W[3][1] = ( D[0][0]*c3 - D[0][1]*c1 + D[0][2]*c0) * id;
  W[3][2] = (-D[3][0]*s3 + D[3][1]*s1 - D[3][2]*s0) * id;
  W[3][3] = ( D[2][0]*s3 - D[2][1]*s1 + D[2][2]*s0) * id;
  #pragma unroll
  for (int r = 0; r < 4; ++r)
    #pragma unroll
    for (int q = 0; q < 4; ++q) D[r][q] = W[r][q];
}
__device__ __forceinline__ unsigned short bf16h_rne(float v) {
  unsigned u = __float_as_uint(v);
  unsigned r = u + 0x7FFFu + ((u >> 16) & 1u);
  return (unsigned short)(r >> 16);
}
__device__ __forceinline__ float bf16_back(unsigned short h) {
  return __uint_as_float(((unsigned)h) << 16);
}
__device__ __forceinline__ void split8(const float v[8], short8v &hi, short8v &lo) {
  #pragma unroll
  for (int j = 0; j < 8; ++j) {
    unsigned short h = bf16h_rne(v[j]);
    hi[j] = (short)h;
    lo[j] = (short)bf16h_rne(v[j] - bf16_back(h));
  }
}

// double-buffered block-GJ step, stride 68 (64x64), 256 threads
__device__ __forceinline__ void gj_step64(const float* __restrict__ src,
                                          float* __restrict__ dst,
                                          int b, int ig, int jg) {
  float D[4][4], C[4][4], R[4][4], T4[4][4], W[4][4];
  #pragma unroll
  for (int r = 0; r < 4; ++r) {
    ld4(&src[(4*b + r)*68 + 4*b],  D[r]);
    ld4(&src[(4*ig + r)*68 + 4*b], C[r]);
    ld4(&src[(4*b + r)*68 + 4*jg], R[r]);
    ld4(&src[(4*ig + r)*68 + 4*jg], T4[r]);
  }
  inv4(D);
  if (ig == b) {
    if (jg == b) {
      #pragma unroll
      for (int r = 0; r < 4; ++r)
        #pragma unroll
        for (int q = 0; q < 4; ++q) W[r][q] = D[r][q];
    } else {
      mm4(W, D, R);
    }
  } else {
    float E[4][4];
    mm4(E, C, D);
    if (jg == b) {
      #pragma unroll
      for (int r = 0; r < 4; ++r)
        #pragma unroll
        for (int q = 0; q < 4; ++q) W[r][q] = -E[r][q];
    } else {
      #pragma unroll
      for (int r = 0; r < 4; ++r)
        #pragma unroll
        for (int q = 0; q < 4; ++q) {
          float s = T4[r][q];
          #pragma unroll
          for (int k = 0; k < 4; ++k) s -= E[r][k] * R[k][q];
          W[r][q] = s;
        }
    }
  }
  #pragma unroll
  for (int r = 0; r < 4; ++r) st4(&dst[(4*ig + r)*68 + 4*jg], W[r]);
  __syncthreads();
}

// double-buffered block-GJ step, stride 52 (48x48), threads 0..143
__device__ __forceinline__ void gj_step48(const float* __restrict__ src,
                                          float* __restrict__ dst,
                                          int b, int tid) {
  const bool act = tid < 144;
  const int ig = tid / 12, jg = tid - (tid / 12) * 12;
  float D[4][4], C[4][4], R[4][4], T4[4][4], W[4][4];
  if (act) {
    #pragma unroll
    for (int r = 0; r < 4; ++r) {
      ld4(&src[(4*b + r)*52 + 4*b],  D[r]);
      ld4(&src[(4*ig + r)*52 + 4*b], C[r]);
      ld4(&src[(4*b + r)*52 + 4*jg], R[r]);
      ld4(&src[(4*ig + r)*52 + 4*jg], T4[r]);
    }
    inv4(D);
    if (ig == b) {
      if (jg == b) {
        #pragma unroll
        for (int r = 0; r < 4; ++r)
          #pragma unroll
          for (int q = 0; q < 4; ++q) W[r][q] = D[r][q];
      } else {
        mm4(W, D, R);
      }
    } else {
      float E[4][4];
      mm4(E, C, D);
      if (jg == b) {
        #pragma unroll
        for (int r = 0; r < 4; ++r)
          #pragma unroll
          for (int q = 0; q < 4; ++q) W[r][q] = -E[r][q];
      } else {
        #pragma unroll
        for (int r = 0; r < 4; ++r)
          #pragma unroll
          for (int q = 0; q < 4; ++q) {
            float s = T4[r][q];
            #pragma unroll
            for (int k = 0; k < 4; ++k) s -= E[r][k] * R[k][q];
            W[r][q] = s;
          }
      }
    }
    #pragma unroll
    for (int r = 0; r < 4; ++r) st4(&dst[(4*ig + r)*52 + 4*jg], W[r]);
  }
  __syncthreads();
}

// ---------------------------------------------------------------- prep1
__global__ __launch_bounds__(256, 1) void prep1_kernel(
    const float* __restrict__ Qg, const float* __restrict__ Ag,
    const float* __restrict__ Gg,
    float* __restrict__ Sg, float* __restrict__ Tg, float* __restrict__ Kig)
{
  __shared__ float sMa[64*68];   // M1 ping -> S
  __shared__ float sMb[64*68];   // M1 pong -> T (stride 48)
  __shared__ float sK [48*52];   // K2 ping -> Ki
  __shared__ float sJx[48*68];   // Jx staged; also GJ48 pong (48*52)

#define SM_(i,j) sMa[(i)*68+(j)]
#define TT_(i,j) sMb[(i)*48+(j)]
#define SK_(i,j) sK[(i)*52+(j)]
#define JX_(a,k) sJx[(a)*68+(k)]

  const int tid = threadIdx.x;
  const int ig = tid >> 4, jg = tid & 15;

  // stage Jx = [A;G] and M1 = Q + I
  {
    const float4* A4 = (const float4*)Ag;
    const float4* G4 = (const float4*)Gg;
    {
      int a = tid >> 4, kc = tid & 15;
      float v[4]; ld4((const float*)&A4[tid], v);
      st4(&JX_(a, kc*4), v);
    }
    for (int t = tid; t < 512; t += 256) {
      int a = t >> 4, kc = t & 15;
      float v[4]; ld4((const float*)&G4[t], v);
      st4(&JX_(16 + a, kc*4), v);
    }
    const float4* Q4 = (const float4*)Qg;
    for (int t = tid; t < 1024; t += 256) {
      int i = t >> 4, kc = t & 15;
      float v[4]; ld4((const float*)&Q4[t], v);
      st4(&SM_(i, kc*4), v);
    }
  }
  __syncthreads();
  if (tid < 64) SM_(tid, tid) += 1.0f;
  __syncthreads();

  // block-GJ 64 (dbuf, 16 steps) -> S in sMa
  #pragma unroll 1
  for (int p = 0; p < 8; ++p) {
    gj_step64(sMa, sMb, 2*p,     ig, jg);
    gj_step64(sMb, sMa, 2*p + 1, ig, jg);
  }

  // T = S Jx^T : 4x3 register tile/thread
  {
    const int i0 = 4*ig, j0 = 3*jg;
    float acc[4][3] = {};
    #pragma unroll 4
    for (int kq = 0; kq < 16; ++kq) {
      float sv[4][4], jv[3][4];
      ld4(&SM_(i0+0, kq*4), sv[0]); ld4(&SM_(i0+1, kq*4), sv[1]);
      ld4(&SM_(i0+2, kq*4), sv[2]); ld4(&SM_(i0+3, kq*4), sv[3]);
      ld4(&JX_(j0+0, kq*4), jv[0]); ld4(&JX_(j0+1, kq*4), jv[1]);
      ld4(&JX_(j0+2, kq*4), jv[2]);
      #pragma unroll
      for (int r = 0; r < 4; ++r)
        #pragma unroll
        for (int c = 0; c < 3; ++c)
          #pragma unroll
          for (int s = 0; s < 4; ++s)
            acc[r][c] += sv[r][s] * jv[c][s];
    }
    __syncthreads();
    #pragma unroll
    for (int r = 0; r < 4; ++r)
      #pragma unroll
      for (int c = 0; c < 3; ++c)
        TT_(i0+r, j0+c) = acc[r][c];
  }
  __syncthreads();

  // K2 = Jx T + diag(0,I32)  (192 threads, 3x4 tiles)
  if (tid < 192) {
    int ag = tid / 12, bg = tid - ag*12;
    int a0 = ag*3, b0 = bg*4;
    float acc[3][4] = {};
    #pragma unroll 4
    for (int k = 0; k < 64; ++k) {
      float4 tb = *(const float4*)&TT_(k,b0);
      #pragma unroll
      for (int r = 0; r < 3; ++r) {
        float jv = JX_(a0 + r, k);
        acc[r][0] += jv*tb.x; acc[r][1] += jv*tb.y;
        acc[r][2] += jv*tb.z; acc[r][3] += jv*tb.w;
      }
    }
    #pragma unroll
    for (int r = 0; r < 3; ++r)
      #pragma unroll
      for (int q = 0; q < 4; ++q) {
        int a = a0 + r, b = b0 + q;
        SK_(a,b) = acc[r][q] + ((a == b && a >= 16) ? 1.0f : 0.0f);
      }
  }
  __syncthreads();

  // block-GJ 48 (dbuf; pong overlays dead Jx region) -> Ki in sK
  {
    float* KP = sJx;   // 48*52 = 2496 <= 48*68
    #pragma unroll 1
    for (int p = 0; p < 6; ++p) {
      gj_step48(sK, KP, 2*p,     tid);
      gj_step48(KP, sK, 2*p + 1, tid);
    }
  }

  // write S (64x64), T (64x48), Ki (48x48) to ws
  #pragma unroll 1
  for (int t = tid; t < 1024; t += 256) {
    int i = t >> 4, q = t & 15;
    float v[4]; ld4(&SM_(i, q*4), v); st4(&Sg[i*64 + q*4], v);
  }
  #pragma unroll 1
  for (int t = tid; t < 768; t += 256) {
    int i = t / 12, q = t - 12*(t/12);
    float v[4]; ld4(&TT_(i, q*4), v); st4(&Tg[i*48 + q*4], v);
  }
  #pragma unroll 1
  for (int t = tid; t < 576; t += 256) {
    int k = t / 12, q = t - 12*(t/12);
    float v[4]; ld4(&SK_(k, q*4), v); st4(&Kig[k*48 + q*4], v);
  }
#undef SM_
#undef TT_
#undef SK_
#undef JX_
}

// ---------------------------------------------------------------- prep2
__global__ __launch_bounds__(256, 1) void prep2_kernel(
    const float* __restrict__ Sg, const float* __restrict__ Tg,
    const float* __restrict__ Kig,
    float* __restrict__ Pg, float* __restrict__ Bg)
{
  __shared__ float sT [64*48];
  __shared__ float sKi[48*48];
  __shared__ float sR2[48*96];
  __shared__ float sS [24*64];

  const int tid = threadIdx.x;
  const int b   = blockIdx.x;        // rows [24b, 24b+24)
  const int r0b = 24 * b;

  #pragma unroll 1
  for (int t = tid; t < 768; t += 256) {
    float v[4]; ld4(&Tg[t*4], v); st4(&sT[t*4], v);
  }
  #pragma unroll 1
  for (int t = tid; t < 576; t += 256) {
    float v[4]; ld4(&Kig[t*4], v); st4(&sKi[t*4], v);
  }
  #pragma unroll 1
  for (int t = tid; t < 384; t += 256) {
    int ri = t >> 4, q = t & 15;
    if (r0b + ri < 64) {
      float v[4]; ld4(&Sg[(r0b + ri)*64 + q*4], v); st4(&sS[ri*64 + q*4], v);
    }
  }
  __syncthreads();

  #pragma unroll 1
  for (int t = tid; t < 48*64; t += 256) {
    int k = t >> 6, c = t & 63;
    float acc = 0.0f;
    #pragma unroll 4
    for (int m = 0; m < 48; m += 4) {
      float kv[4], tv[4];
      ld4(&sKi[k*48 + m], kv); ld4(&sT[c*48 + m], tv);
      acc += kv[0]*tv[0] + kv[1]*tv[1] + kv[2]*tv[2] + kv[3]*tv[3];
    }
    sR2[k*96 + c] = acc;
  }
  #pragma unroll 1
  for (int t = tid; t < 48*32; t += 256) {
    int k = t >> 5, j = t & 31;
    sR2[k*96 + 64 + j] = sKi[k*48 + 16 + j];
  }
  __syncthreads();

  #pragma unroll 1
  for (int t = tid; t < 24*48; t += 256) {
    int c = r0b + t / 48, k = t - 48*(t/48);
    Bg[c*112 + 64 + k] = sR2[k*96 + c];
  }

  #pragma unroll 1
  for (int task = tid; task < 576; task += 256) {
    int ri = task / 24, jq = task - 24*(task/24);
    int i = r0b + ri, j0 = jq*4;
    if (i < 64) {
      float acc[4];
      #pragma unroll
      for (int q = 0; q < 4; ++q)
        acc[q] = (j0 < 64) ? sS[ri*64 + j0 + q] : 0.0f;
      #pragma unroll 4
      for (int m = 0; m < 48; m += 4) {
        float tv[4], rv[4][4];
        ld4(&sT[i*48 + m], tv);
        ld4(&sR2[(m+0)*96 + j0], rv[0]);
        ld4(&sR2[(m+1)*96 + j0], rv[1]);
        ld4(&sR2[(m+2)*96 + j0], rv[2]);
        ld4(&sR2[(m+3)*96 + j0], rv[3]);
        #pragma unroll
        for (int q = 0; q < 4; ++q)
          #pragma unroll
          for (int s = 0; s < 4; ++s)
            acc[q] -= tv[s] * rv[s][q];
      }
      #pragma unroll
      for (int q = 0; q < 4; ++q) {
        int j = j0 + q;
        Pg[i*96 + j] = acc[q];
        if (j < 64) Bg[i*112 + j] = -acc[q];
      }
    } else {
      int a = i - 64;
      #pragma unroll
      for (int q = 0; q < 4; ++q) {
        int j = j0 + q;
        float v = (i == j ? 1.0f : 0.0f) - sR2[(16 + a)*96 + j];
        Pg[i*96 + j] = v;
        if (j < 64) Bg[i*112 + j] = -v;
      }
    }
  }
}

// ---------------------------------------------------------------- kernel B
#define EB 16   // elements per block; grid = 256 blocks x 384 threads

__global__ __launch_bounds__(384, 1) void iter_kernel(
    const float* __restrict__ xg, const float* __restrict__ pg,
    const float* __restrict__ Pg, const float* __restrict__ Bg,
    float* __restrict__ outg)
{
  // MFMA split-bf16. Wave w owns row-tile 16w. xo kept in 4 f32 registers
  // across iterations (D-layout == update layout); LDS holds only the bf16
  // hi/lo splits of x (double-buffered). (round-18 exact)
  __shared__ short sXh[2][EB*104], sXl[2][EB*104];

  const int tid   = threadIdx.x;    // 0..383
  const int gbase = blockIdx.x * EB;
  const int w     = tid >> 6;
  const int lane  = tid & 63;
  const int e     = lane & 15;
  const int g     = lane >> 4;
  const int row0  = 16 * w;
  const int rbase = row0 + 4*g;

  // P fragments (A operand), hi/lo, register-resident
  short8v pfh[3], pfl[3];
  #pragma unroll
  for (int kc = 0; kc < 3; ++kc) {
    float v[8];
    const float* src = Pg + (row0 + e)*96 + 32*kc + 8*g;
    ld4(src, v); ld4(src + 4, v + 4);
    split8(v, pfh[kc], pfl[kc]);
  }

  // x state: my 4 values in registers; splits to LDS buffer 0
  float xo[4];
  ld4(xg + (size_t)(gbase + e)*96 + rbase, xo);
  {
    short4v hv, lv;
    #pragma unroll
    for (int r = 0; r < 4; ++r) {
      unsigned short h = bf16h_rne(xo[r]);
      hv[r] = (short)h;
      lv[r] = (short)bf16h_rne(xo[r] - bf16_back(h));
    }
    *(short4v*)&sXh[0][e*104 + rbase] = hv;
    *(short4v*)&sXl[0][e*104 + rbase] = lv;
  }

  // c = Bmat @ parms via MFMA (global reads; K=112 padded to 128)
  float4v cfrag = {0.f, 0.f, 0.f, 0.f};
  #pragma unroll
  for (int kc = 0; kc < 4; ++kc) {
    const int kbase = 32*kc + 8*g;
    float v[8];
    short8v ah, al, bh, bl;
    if (kbase < 112) {
      const float* src = Bg + (row0 + e)*112 + kbase;
      ld4(src, v); ld4(src + 4, v + 4);
    } else {
      #pragma unroll
      for (int j = 0; j < 8; ++j) v[j] = 0.f;
    }
    split8(v, ah, al);
    if (kbase < 112) {
      const float* src = pg + (size_t)(gbase + e)*112 + kbase;
      ld4(src, v); ld4(src + 4, v + 4);
    } else {
      #pragma unroll
      for (int j = 0; j < 8; ++j) v[j] = 0.f;
    }
    split8(v, bh, bl);
    cfrag = MFMA_BF16(ah, bh, cfrag, 0, 0, 0);
    cfrag = MFMA_BF16(ah, bl, cfrag, 0, 0, 0);
    cfrag = MFMA_BF16(al, bh, cfrag, 0, 0, 0);
  }

  __syncthreads();   // x splits visible

  const float lob = (row0 < 64) ? -1000.f : 0.f;
  int cur = 0;

  #pragma unroll 1
  for (int it = 0; it < 10; ++it) {
    const short* xhp = &sXh[cur][0];
    const short* xlp = &sXl[cur][0];
    float4v accs0 = cfrag;
    float4v accs1 = {0.f, 0.f, 0.f, 0.f};
    float4v accs2 = {0.f, 0.f, 0.f, 0.f};
    {
      int off = e*104 + 8*g;
      short8v xh0 = *(const short8v*)&xhp[off];
      short8v xl0 = *(const short8v*)&xlp[off];
      short8v xh1 = *(const short8v*)&xhp[off + 32];
      short8v xl1 = *(const short8v*)&xlp[off + 32];
      short8v xh2 = *(const short8v*)&xhp[off + 64];
      short8v xl2 = *(const short8v*)&xlp[off + 64];
      accs0 = MFMA_BF16(pfh[0], xh0, accs0, 0, 0, 0);
      accs1 = MFMA_BF16(pfh[1], xh1, accs1, 0, 0, 0);
      accs2 = MFMA_BF16(pfh[2], xh2, accs2, 0, 0, 0);
      accs0 = MFMA_BF16(pfh[0], xl0, accs0, 0, 0, 0);
      accs1 = MFMA_BF16(pfh[1], xl1, accs1, 0, 0, 0);
      accs2 = MFMA_BF16(pfh[2], xl2, accs2, 0, 0, 0);
      accs0 = MFMA_BF16(pfl[0], xh0, accs0, 0, 0, 0);
      accs1 = MFMA_BF16(pfl[1], xh1, accs1, 0, 0, 0);
      accs2 = MFMA_BF16(pfl[2], xh2, accs2, 0, 0, 0);
    }
    float4v acc = accs0 + accs1 + accs2;

    if (it < 9) {
      short4v hv, lv;
      #pragma unroll
      for (int r = 0; r < 4; ++r) {
        float y = acc[r];
        float z = fminf(fmaxf(2.f*y - xo[r], lob), 1000.f);
        float xn = xo[r] + z - y;
        xo[r] = xn;
        unsigned short h = bf16h_rne(xn);
        hv[r] = (short)h;
        lv[r] = (short)bf16h_rne(xn - bf16_back(h));
      }
      *(short4v*)&sXh[cur ^ 1][e*104 + rbase] = hv;
      *(short4v*)&sXl[cur ^ 1][e*104 + rbase] = lv;
      __syncthreads();
      cur ^= 1;
    } else {
      if (row0 < 64) {
        *(float4*)&outg[(gbase + e)*64 + rbase] =
            make_float4(acc[0], acc[1], acc[2], acc[3]);
      }
    }
  }
}

// ---------------------------------------------------------------- launch
extern "C" void kernel_launch(void* const* d_in, const int* in_sizes, int n_in,
                              void* d_out, int out_size, void* d_ws, size_t ws_size,
                              hipStream_t stream) {
  const float* x     = (const float*)d_in[0];   // (4096, 96)
  const float* parms = (const float*)d_in[1];   // (4096, 112)
  const float* Qg    = (const float*)d_in[2];   // (64, 64)
  const float* Ag    = (const float*)d_in[3];   // (16, 64)
  const float* Gg    = (const float*)d_in[4];   // (32, 64)
  float* out = (float*)d_out;                   // (4096, 64)

  float* ws  = (float*)d_ws;
  float* Pg  = ws;                  // 96*96  = 9216
  float* Bg  = ws + 9216;           // 96*112 = 10752
  float* Sg  = ws + 19968;          // 64*64  = 4096
  float* Tg  = ws + 24064;          // 64*48  = 3072
  float* Kig = ws + 27136;          // 48*48  = 2304

  prep1_kernel<<<1, 256, 0, stream>>>(Qg, Ag, Gg, Sg, Tg, Kig);
  prep2_kernel<<<4, 256, 0, stream>>>(Sg, Tg, Kig, Pg, Bg);
  iter_kernel<<<4096 / EB, 384, 0, stream>>>(x, parms, Pg, Bg, out);
}

// Round 22
// 52.570 us; speedup vs baseline: 1.2654x; 1.0561x over previous
//
#include <hip/hip_runtime.h>

// DR splitting solver. BATCH=4096, N=96, M=48. prox_g1 affine: y = P x + Bmat p.
//   S=(I+Q)^{-1}; T=S Jx^T; K2=Jx T+diag(0,I32); R2=K2^{-1}[T^T|E];
//   P=diag(S,I)-[T;E^T]R2; Bmat=[-P[:,:64] | R2^T]
// Iterate 10x: y=Px+c; x += clamp(2y-x,l,u)-y; out=y[:64].
//
// Round-21 lesson: GJ64 is LDS-pipe-issue bound (~80 b128/step on 1 CU) --
// inv4 variants are noise. Round-22: replace GJ64 with CHEBYSHEV solves of
// (I+Q)Z=[I|Jx^T] (112 independent columns, 14 blocks x 8 cols). Bounds
// guaranteed: Q>=0 => lmin>=1; lmax<=Gershgorin B. 20 iters, factor~0.44.
// M-frags register-resident, matvec=6 MFMA, x/r/d in registers, 1 barrier/iter.
// S stored col-as-row (symmetric). GJ48 kept (lmin(K2) not certifiable) in
// slim prepB. prep2+iter = round-18 exact.

typedef __attribute__((ext_vector_type(8))) short short8v;
typedef __attribute__((ext_vector_type(4))) short short4v;
typedef __attribute__((ext_vector_type(4))) float float4v;

#define MFMA_BF16 __builtin_amdgcn_mfma_f32_16x16x32_bf16

__device__ __forceinline__ void ld4(const float* p, float* d) {
  float4 v = *(const float4*)p;
  d[0] = v.x; d[1] = v.y; d[2] = v.z; d[3] = v.w;
}
__device__ __forceinline__ void st4(float* p, const float* s) {
  *(float4*)p = make_float4(s[0], s[1], s[2], s[3]);
}
__device__ __forceinline__ float fastrcp(float x) {
  float r = __builtin_amdgcn_rcpf(x);
  return r * (2.0f - x * r);
}
__device__ __forceinline__ void mm4(float W[4][4], const float A[4][4], const float B[4][4]) {
  #pragma unroll
  for (int r = 0; r < 4; ++r)
    #pragma unroll
    for (int q = 0; q < 4; ++q) {
      float s = A[r][0]*B[0][q];
      #pragma unroll
      for (int k = 1; k < 4; ++k) s += A[r][k]*B[k][q];
      W[r][q] = s;
    }
}
// r18 pivot-based inv4 (no pivoting needed: SPD principal blocks)
__device__ __forceinline__ void inv4(float D[4][4]) {
  #pragma unroll
  for (int p = 0; p < 4; ++p) {
    float pi = fastrcp(D[p][p]);
    D[p][p] = pi;
    #pragma unroll
    for (int q = 0; q < 4; ++q) if (q != p) D[p][q] *= pi;
    #pragma unroll
    for (int i = 0; i < 4; ++i) if (i != p) {
      float f = D[i][p];
      #pragma unroll
      for (int q = 0; q < 4; ++q) if (q != p) D[i][q] -= f * D[p][q];
      D[i][p] = -f * pi;
    }
  }
}
__device__ __forceinline__ unsigned short bf16h_rne(float v) {
  unsigned u = __float_as_uint(v);
  unsigned r = u + 0x7FFFu + ((u >> 16) & 1u);
  return (unsigned short)(r >> 16);
}
__device__ __forceinline__ float bf16_back(unsigned short h) {
  return __uint_as_float(((unsigned)h) << 16);
}
__device__ __forceinline__ void split8(const float v[8], short8v &hi, short8v &lo) {
  #pragma unroll
  for (int j = 0; j < 8; ++j) {
    unsigned short h = bf16h_rne(v[j]);
    hi[j] = (short)h;
    lo[j] = (short)bf16h_rne(v[j] - bf16_back(h));
  }
}

// ---------------------------------------------------------------- prepA
// Chebyshev solve (I+Q) Z = [I | Jx^T]; 14 blocks x 8 columns each.
// Wave w owns output rows 16w..16w+15; lane (e,g): col e, rows 16w+4g..+3.
#define CHEB_ITERS 20

__global__ __launch_bounds__(256, 1) void prepA_kernel(
    const float* __restrict__ Qg, const float* __restrict__ Ag,
    const float* __restrict__ Gg,
    float* __restrict__ Sg, float* __restrict__ Tg)
{
  __shared__ short sDh[2][16*104], sDl[2][16*104];
  __shared__ float sRed[68];

  const int tid  = threadIdx.x;
  const int w    = tid >> 6, lane = tid & 63;
  const int e    = lane & 15, g = lane >> 4;
  const int row0 = 16*w, rbase = row0 + 4*g;
  const int colg = 8*(int)blockIdx.x + e;   // valid when e<8

  // Gershgorin row sums of M1 = I+Q: sum_j |Q_ij| + 1  (threads 0..63)
  if (tid < 64) {
    float s = 1.0f;
    #pragma unroll 4
    for (int kq = 0; kq < 16; ++kq) {
      float v[4]; ld4(&Qg[tid*64 + kq*4], v);
      s += fabsf(v[0]) + fabsf(v[1]) + fabsf(v[2]) + fabsf(v[3]);
    }
    sRed[tid] = s;
  }
  __syncthreads();
  if (tid == 0) {
    float b = sRed[0];
    #pragma unroll 4
    for (int k = 1; k < 64; ++k) b = fmaxf(b, sRed[k]);
    sRed[64] = b;
  }

  // M-frags (A operand): row row0+e of M1, hi/lo splits (register-resident)
  short8v mah[2], mal[2];
  #pragma unroll
  for (int ks = 0; ks < 2; ++ks) {
    const int kb = 32*ks + 8*g;
    float v[8];
    ld4(&Qg[(row0+e)*64 + kb], v);
    ld4(&Qg[(row0+e)*64 + kb + 4], v + 4);
    #pragma unroll
    for (int j = 0; j < 8; ++j)
      if (row0 + e == kb + j) v[j] += 1.0f;
    split8(v, mah[ks], mal[ks]);
  }

  __syncthreads();
  const float B     = sRed[64];
  const float theta = 0.5f*(B + 1.0f);
  const float delta = 0.5f*(B - 1.0f);
  const float sigma = theta / delta;
  float rho = delta / theta;          // 1/sigma

  // rhs b; state x=0, r=b, d=b/theta (registers; lanes e>=8 are zero cols)
  float xv[4] = {0.f,0.f,0.f,0.f}, rv[4], dv[4];
  #pragma unroll
  for (int r = 0; r < 4; ++r) {
    float bb = 0.f;
    if (e < 8) {
      if (colg < 64) {
        bb = (rbase + r == colg) ? 1.0f : 0.0f;
      } else {
        int jr = colg - 64;
        bb = (jr < 16) ? Ag[jr*64 + rbase + r] : Gg[(jr-16)*64 + rbase + r];
      }
    }
    rv[r] = bb;
    dv[r] = bb / theta;
  }
  {
    short4v hv, lv;
    #pragma unroll
    for (int r = 0; r < 4; ++r) {
      unsigned short h = bf16h_rne(dv[r]);
      hv[r] = (short)h;
      lv[r] = (short)bf16h_rne(dv[r] - bf16_back(h));
    }
    *(short4v*)&sDh[0][e*104 + rbase] = hv;
    *(short4v*)&sDl[0][e*104 + rbase] = lv;
  }
  __syncthreads();

  int cur = 0;
  #pragma unroll 1
  for (int it = 0; it < CHEB_ITERS; ++it) {
    // acc = M1 * d  (split-bf16, 6 MFMA)
    float4v acc = {0.f,0.f,0.f,0.f};
    const short* dh = &sDh[cur][0];
    const short* dl = &sDl[cur][0];
    #pragma unroll
    for (int ks = 0; ks < 2; ++ks) {
      int off = e*104 + 32*ks + 8*g;
      short8v bh = *(const short8v*)&dh[off];
      short8v bl = *(const short8v*)&dl[off];
      acc = MFMA_BF16(mah[ks], bh, acc, 0, 0, 0);
      acc = MFMA_BF16(mah[ks], bl, acc, 0, 0, 0);
      acc = MFMA_BF16(mal[ks], bh, acc, 0, 0, 0);
    }
    float rhon = 1.0f / (2.0f*sigma - rho);
    float ca = rhon * rho, cb = 2.0f*rhon/delta;
    short4v hv, lv;
    #pragma unroll
    for (int r = 0; r < 4; ++r) {
      xv[r] += dv[r];
      rv[r] -= acc[r];
      dv[r] = ca*dv[r] + cb*rv[r];
      unsigned short h = bf16h_rne(dv[r]);
      hv[r] = (short)h;
      lv[r] = (short)bf16h_rne(dv[r] - bf16_back(h));
    }
    rho = rhon;
    *(short4v*)&sDh[cur^1][e*104 + rbase] = hv;
    *(short4v*)&sDl[cur^1][e*104 + rbase] = lv;
    __syncthreads();
    cur ^= 1;
  }

  // write out: S columns (symmetric -> store as rows), T columns (scatter)
  if (e < 8) {
    if (colg < 64) {
      *(float4*)&Sg[colg*64 + rbase] = make_float4(xv[0], xv[1], xv[2], xv[3]);
    } else {
      int j = colg - 64;
      #pragma unroll
      for (int r = 0; r < 4; ++r) Tg[(rbase + r)*48 + j] = xv[r];
    }
  }
}

// double-buffered block-GJ step, stride 52 (48x48), threads 0..143
__device__ __forceinline__ void gj_step48(const float* __restrict__ src,
                                          float* __restrict__ dst,
                                          int b, int tid) {
  const bool act = tid < 144;
  const int ig = tid / 12, jg = tid - (tid / 12) * 12;
  float D[4][4], C[4][4], R[4][4], T4[4][4], W[4][4];
  if (act) {
    #pragma unroll
    for (int r = 0; r < 4; ++r) {
      ld4(&src[(4*b + r)*52 + 4*b],  D[r]);
      ld4(&src[(4*ig + r)*52 + 4*b], C[r]);
      ld4(&src[(4*b + r)*52 + 4*jg], R[r]);
      ld4(&src[(4*ig + r)*52 + 4*jg], T4[r]);
    }
    inv4(D);
    if (ig == b) {
      if (jg == b) {
        #pragma unroll
        for (int r = 0; r < 4; ++r)
          #pragma unroll
          for (int q = 0; q < 4; ++q) W[r][q] = D[r][q];
      } else {
        mm4(W, D, R);
      }
    } else {
      float E[4][4];
      mm4(E, C, D);
      if (jg == b) {
        #pragma unroll
        for (int r = 0; r < 4; ++r)
          #pragma unroll
          for (int q = 0; q < 4; ++q) W[r][q] = -E[r][q];
      } else {
        #pragma unroll
        for (int r = 0; r < 4; ++r)
          #pragma unroll
          for (int q = 0; q < 4; ++q) {
            float s = T4[r][q];
            #pragma unroll
            for (int k = 0; k < 4; ++k) s -= E[r][k] * R[k][q];
            W[r][q] = s;
          }
      }
    }
    #pragma unroll
    for (int r = 0; r < 4; ++r) st4(&dst[(4*ig + r)*52 + 4*jg], W[r]);
  }
  __syncthreads();
}

// ---------------------------------------------------------------- prepB
// 1 block: K2 = Jx T + diag(0,I32); GJ48 -> Ki.
__global__ __launch_bounds__(256, 1) void prepB_kernel(
    const float* __restrict__ Ag, const float* __restrict__ Gg,
    const float* __restrict__ Tg, float* __restrict__ Kig)
{
  __shared__ float sT [64*48];   // T (stride 48)
  __shared__ float sK [48*52];   // K2 ping -> Ki
  __shared__ float sJx[48*68];   // Jx staged; later GJ48 pong (48*52)

#define TT_(i,j) sT[(i)*48+(j)]
#define SK_(i,j) sK[(i)*52+(j)]
#define JX_(a,k) sJx[(a)*68+(k)]

  const int tid = threadIdx.x;

  // stage Jx and T
  {
    const float4* A4 = (const float4*)Ag;
    const float4* G4 = (const float4*)Gg;
    {
      int a = tid >> 4, kc = tid & 15;
      float v[4]; ld4((const float*)&A4[tid], v);
      st4(&JX_(a, kc*4), v);
    }
    for (int t = tid; t < 512; t += 256) {
      int a = t >> 4, kc = t & 15;
      float v[4]; ld4((const float*)&G4[t], v);
      st4(&JX_(16 + a, kc*4), v);
    }
    for (int t = tid; t < 768; t += 256) {
      float v[4]; ld4(&Tg[t*4], v); st4(&sT[t*4], v);
    }
  }
  __syncthreads();

  // K2 = Jx T + diag(0,I32)  (192 threads, 3x4 tiles)
  if (tid < 192) {
    int ag = tid / 12, bg = tid - ag*12;
    int a0 = ag*3, b0 = bg*4;
    float acc[3][4] = {};
    #pragma unroll 4
    for (int k = 0; k < 64; ++k) {
      float4 tb = *(const float4*)&TT_(k,b0);
      #pragma unroll
      for (int r = 0; r < 3; ++r) {
        float jv = JX_(a0 + r, k);
        acc[r][0] += jv*tb.x; acc[r][1] += jv*tb.y;
        acc[r][2] += jv*tb.z; acc[r][3] += jv*tb.w;
      }
    }
    #pragma unroll
    for (int r = 0; r < 3; ++r)
      #pragma unroll
      for (int q = 0; q < 4; ++q) {
        int a = a0 + r, b = b0 + q;
        SK_(a,b) = acc[r][q] + ((a == b && a >= 16) ? 1.0f : 0.0f);
      }
  }
  __syncthreads();

  // block-GJ 48 (dbuf; pong overlays dead Jx region) -> Ki in sK
  {
    float* KP = sJx;   // 48*52 = 2496 <= 48*68
    #pragma unroll 1
    for (int p = 0; p < 6; ++p) {
      gj_step48(sK, KP, 2*p,     tid);
      gj_step48(KP, sK, 2*p + 1, tid);
    }
  }

  // write Ki
  #pragma unroll 1
  for (int t = tid; t < 576; t += 256) {
    int k = t / 12, q = t - 12*(t/12);
    float v[4]; ld4(&SK_(k, q*4), v); st4(&Kig[k*48 + q*4], v);
  }
#undef TT_
#undef SK_
#undef JX_
}

// ---------------------------------------------------------------- prep2
__global__ __launch_bounds__(256, 1) void prep2_kernel(
    const float* __restrict__ Sg, const float* __restrict__ Tg,
    const float* __restrict__ Kig,
    float* __restrict__ Pg, float* __restrict__ Bg)
{
  __shared__ float sT [64*48];
  __shared__ float sKi[48*48];
  __shared__ float sR2[48*96];
  __shared__ float sS [24*64];

  const int tid = threadIdx.x;
  const int b   = blockIdx.x;        // rows [24b, 24b+24)
  const int r0b = 24 * b;

  #pragma unroll 1
  for (int t = tid; t < 768; t += 256) {
    float v[4]; ld4(&Tg[t*4], v); st4(&sT[t*4], v);
  }
  #pragma unroll 1
  for (int t = tid; t < 576; t += 256) {
    float v[4]; ld4(&Kig[t*4], v); st4(&sKi[t*4], v);
  }
  #pragma unroll 1
  for (int t = tid; t < 384; t += 256) {
    int ri = t >> 4, q = t & 15;
    if (r0b + ri < 64) {
      float v[4]; ld4(&Sg[(r0b + ri)*64 + q*4], v); st4(&sS[ri*64 + q*4], v);
    }
  }
  __syncthreads();

  #pragma unroll 1
  for (int t = tid; t < 48*64; t += 256) {
    int k = t >> 6, c = t & 63;
    float acc = 0.0f;
    #pragma unroll 4
    for (int m = 0; m < 48; m += 4) {
      float kv[4], tv[4];
      ld4(&sKi[k*48 + m], kv); ld4(&sT[c*48 + m], tv);
      acc += kv[0]*tv[0] + kv[1]*tv[1] + kv[2]*tv[2] + kv[3]*tv[3];
    }
    sR2[k*96 + c] = acc;
  }
  #pragma unroll 1
  for (int t = tid; t < 48*32; t += 256) {
    int k = t >> 5, j = t & 31;
    sR2[k*96 + 64 + j] = sKi[k*48 + 16 + j];
  }
  __syncthreads();

  #pragma unroll 1
  for (int t = tid; t < 24*48; t += 256) {
    int c = r0b + t / 48, k = t - 48*(t/48);
    Bg[c*112 + 64 + k] = sR2[k*96 + c];
  }

  #pragma unroll 1
  for (int task = tid; task < 576; task += 256) {
    int ri = task / 24, jq = task - 24*(task/24);
    int i = r0b + ri, j0 = jq*4;
    if (i < 64) {
      float acc[4];
      #pragma unroll
      for (int q = 0; q < 4; ++q)
        acc[q] = (j0 < 64) ? sS[ri*64 + j0 + q] : 0.0f;
      #pragma unroll 4
      for (int m = 0; m < 48; m += 4) {
        float tv[4], rv[4][4];
        ld4(&sT[i*48 + m], tv);
        ld4(&sR2[(m+0)*96 + j0], rv[0]);
        ld4(&sR2[(m+1)*96 + j0], rv[1]);
        ld4(&sR2[(m+2)*96 + j0], rv[2]);
        ld4(&sR2[(m+3)*96 + j0], rv[3]);
        #pragma unroll
        for (int q = 0; q < 4; ++q)
          #pragma unroll
          for (int s = 0; s < 4; ++s)
            acc[q] -= tv[s] * rv[s][q];
      }
      #pragma unroll
      for (int q = 0; q < 4; ++q) {
        int j = j0 + q;
        Pg[i*96 + j] = acc[q];
        if (j < 64) Bg[i*112 + j] = -acc[q];
      }
    } else {
      int a = i - 64;
      #pragma unroll
      for (int q = 0; q < 4; ++q) {
        int j = j0 + q;
        float v = (i == j ? 1.0f : 0.0f) - sR2[(16 + a)*96 + j];
        Pg[i*96 + j] = v;
        if (j < 64) Bg[i*112 + j] = -v;
      }
    }
  }
}

// ---------------------------------------------------------------- kernel B
#define EB 16   // elements per block; grid = 256 blocks x 384 threads

__global__ __launch_bounds__(384, 1) void iter_kernel(
    const float* __restrict__ xg, const float* __restrict__ pg,
    const float* __restrict__ Pg, const float* __restrict__ Bg,
    float* __restrict__ outg)
{
  // round-18 exact: MFMA split-bf16, xo in registers, x splits in LDS dbuf.
  __shared__ short sXh[2][EB*104], sXl[2][EB*104];

  const int tid   = threadIdx.x;    // 0..383
  const int gbase = blockIdx.x * EB;
  const int w     = tid >> 6;
  const int lane  = tid & 63;
  const int e     = lane & 15;
  const int g     = lane >> 4;
  const int row0  = 16 * w;
  const int rbase = row0 + 4*g;

  short8v pfh[3], pfl[3];
  #pragma unroll
  for (int kc = 0; kc < 3; ++kc) {
    float v[8];
    const float* src = Pg + (row0 + e)*96 + 32*kc + 8*g;
    ld4(src, v); ld4(src + 4, v + 4);
    split8(v, pfh[kc], pfl[kc]);
  }

  float xo[4];
  ld4(xg + (size_t)(gbase + e)*96 + rbase, xo);
  {
    short4v hv, lv;
    #pragma unroll
    for (int r = 0; r < 4; ++r) {
      unsigned short h = bf16h_rne(xo[r]);
      hv[r] = (short)h;
      lv[r] = (short)bf16h_rne(xo[r] - bf16_back(h));
    }
    *(short4v*)&sXh[0][e*104 + rbase] = hv;
    *(short4v*)&sXl[0][e*104 + rbase] = lv;
  }

  float4v cfrag = {0.f, 0.f, 0.f, 0.f};
  #pragma unroll
  for (int kc = 0; kc < 4; ++kc) {
    const int kbase = 32*kc + 8*g;
    float v[8];
    short8v ah, al, bh, bl;
    if (kbase < 112) {
      const float* src = Bg + (row0 + e)*112 + kbase;
      ld4(src, v); ld4(src + 4, v + 4);
    } else {
      #pragma unroll
      for (int j = 0; j < 8; ++j) v[j] = 0.f;
    }
    split8(v, ah, al);
    if (kbase < 112) {
      const float* src = pg + (size_t)(gbase + e)*112 + kbase;
      ld4(src, v); ld4(src + 4, v + 4);
    } else {
      #pragma unroll
      for (int j = 0; j < 8; ++j) v[j] = 0.f;
    }
    split8(v, bh, bl);
    cfrag = MFMA_BF16(ah, bh, cfrag, 0, 0, 0);
    cfrag = MFMA_BF16(ah, bl, cfrag, 0, 0, 0);
    cfrag = MFMA_BF16(al, bh, cfrag, 0, 0, 0);
  }

  __syncthreads();

  const float lob = (row0 < 64) ? -1000.f : 0.f;
  int cur = 0;

  #pragma unroll 1
  for (int it = 0; it < 10; ++it) {
    const short* xhp = &sXh[cur][0];
    const short* xlp = &sXl[cur][0];
    float4v accs0 = cfrag;
    float4v accs1 = {0.f, 0.f, 0.f, 0.f};
    float4v accs2 = {0.f, 0.f, 0.f, 0.f};
    {
      int off = e*104 + 8*g;
      short8v xh0 = *(const short8v*)&xhp[off];
      short8v xl0 = *(const short8v*)&xlp[off];
      short8v xh1 = *(const short8v*)&xhp[off + 32];
      short8v xl1 = *(const short8v*)&xlp[off + 32];
      short8v xh2 = *(const short8v*)&xhp[off + 64];
      short8v xl2 = *(const short8v*)&xlp[off + 64];
      accs0 = MFMA_BF16(pfh[0], xh0, accs0, 0, 0, 0);
      accs1 = MFMA_BF16(pfh[1], xh1, accs1, 0, 0, 0);
      accs2 = MFMA_BF16(pfh[2], xh2, accs2, 0, 0, 0);
      accs0 = MFMA_BF16(pfh[0], xl0, accs0, 0, 0, 0);
      accs1 = MFMA_BF16(pfh[1], xl1, accs1, 0, 0, 0);
      accs2 = MFMA_BF16(pfh[2], xl2, accs2, 0, 0, 0);
      accs0 = MFMA_BF16(pfl[0], xh0, accs0, 0, 0, 0);
      accs1 = MFMA_BF16(pfl[1], xh1, accs1, 0, 0, 0);
      accs2 = MFMA_BF16(pfl[2], xh2, accs2, 0, 0, 0);
    }
    float4v acc = accs0 + accs1 + accs2;

    if (it < 9) {
      short4v hv, lv;
      #pragma unroll
      for (int r = 0; r < 4; ++r) {
        float y = acc[r];
        float z = fminf(fmaxf(2.f*y - xo[r], lob), 1000.f);
        float xn = xo[r] + z - y;
        xo[r] = xn;
        unsigned short h = bf16h_rne(xn);
        hv[r] = (short)h;
        lv[r] = (short)bf16h_rne(xn - bf16_back(h));
      }
      *(short4v*)&sXh[cur ^ 1][e*104 + rbase] = hv;
      *(short4v*)&sXl[cur ^ 1][e*104 + rbase] = lv;
      __syncthreads();
      cur ^= 1;
    } else {
      if (row0 < 64) {
        *(float4*)&outg[(gbase + e)*64 + rbase] =
            make_float4(acc[0], acc[1], acc[2], acc[3]);
      }
    }
  }
}

// ---------------------------------------------------------------- launch
extern "C" void kernel_launch(void* const* d_in, const int* in_sizes, int n_in,
                              void* d_out, int out_size, void* d_ws, size_t ws_size,
                              hipStream_t stream) {
  const float* x     = (const float*)d_in[0];   // (4096, 96)
  const float* parms = (const float*)d_in[1];   // (4096, 112)
  const float* Qg    = (const float*)d_in[2];   // (64, 64)
  const float* Ag    = (const float*)d_in[3];   // (16, 64)
  const float* Gg    = (const float*)d_in[4];   // (32, 64)
  float* out = (float*)d_out;                   // (4096, 64)

  float* ws  = (float*)d_ws;
  float* Pg  = ws;                  // 96*96  = 9216
  float* Bg  = ws + 9216;           // 96*112 = 10752
  float* Sg  = ws + 19968;          // 64*64  = 4096
  float* Tg  = ws + 24064;          // 64*48  = 3072
  float* Kig = ws + 27136;          // 48*48  = 2304

  prepA_kernel<<<14, 256, 0, stream>>>(Qg, Ag, Gg, Sg, Tg);
  prepB_kernel<<<1, 256, 0, stream>>>(Ag, Gg, Tg, Kig);
  prep2_kernel<<<4, 256, 0, stream>>>(Sg, Tg, Kig, Pg, Bg);
  iter_kernel<<<4096 / EB, 384, 0, stream>>>(x, parms, Pg, Bg, out);
}

// Round 23
// 48.080 us; speedup vs baseline: 1.3836x; 1.0934x over previous
//
#include <hip/hip_runtime.h>

// DR splitting solver. BATCH=4096, N=96, M=48. prox_g1 affine: y = P x + Bmat p.
//   S=(I+Q)^{-1}; T=S Jx^T; K2=Jx T+diag(0,I32); R2=K2^{-1}[T^T|E];
//   P=diag(S,I)-[T;E^T]R2; Bmat=[-P[:,:64] | R2^T]
// Iterate 10x: y=Px+c; x += clamp(2y-x,l,u)-y; out=y[:64].
//
// Round-22: Chebyshev prepA worked (52.6us best). Round-23: prepA trims --
// (a) Gershgorin max via wave shfl_xor reduce (was serial 63-step fmax on
// tid 0 + extra barrier); (b) CHEB_ITERS 20->14 (0.443^14 ~ 1.1e-5 == the
// split-bf16 residual floor; 20 was 9e-8, pure waste). Rest = round-22 exact.

typedef __attribute__((ext_vector_type(8))) short short8v;
typedef __attribute__((ext_vector_type(4))) short short4v;
typedef __attribute__((ext_vector_type(4))) float float4v;

#define MFMA_BF16 __builtin_amdgcn_mfma_f32_16x16x32_bf16

__device__ __forceinline__ void ld4(const float* p, float* d) {
  float4 v = *(const float4*)p;
  d[0] = v.x; d[1] = v.y; d[2] = v.z; d[3] = v.w;
}
__device__ __forceinline__ void st4(float* p, const float* s) {
  *(float4*)p = make_float4(s[0], s[1], s[2], s[3]);
}
__device__ __forceinline__ float fastrcp(float x) {
  float r = __builtin_amdgcn_rcpf(x);
  return r * (2.0f - x * r);
}
__device__ __forceinline__ void mm4(float W[4][4], const float A[4][4], const float B[4][4]) {
  #pragma unroll
  for (int r = 0; r < 4; ++r)
    #pragma unroll
    for (int q = 0; q < 4; ++q) {
      float s = A[r][0]*B[0][q];
      #pragma unroll
      for (int k = 1; k < 4; ++k) s += A[r][k]*B[k][q];
      W[r][q] = s;
    }
}
__device__ __forceinline__ void inv4(float D[4][4]) {
  #pragma unroll
  for (int p = 0; p < 4; ++p) {
    float pi = fastrcp(D[p][p]);
    D[p][p] = pi;
    #pragma unroll
    for (int q = 0; q < 4; ++q) if (q != p) D[p][q] *= pi;
    #pragma unroll
    for (int i = 0; i < 4; ++i) if (i != p) {
      float f = D[i][p];
      #pragma unroll
      for (int q = 0; q < 4; ++q) if (q != p) D[i][q] -= f * D[p][q];
      D[i][p] = -f * pi;
    }
  }
}
__device__ __forceinline__ unsigned short bf16h_rne(float v) {
  unsigned u = __float_as_uint(v);
  unsigned r = u + 0x7FFFu + ((u >> 16) & 1u);
  return (unsigned short)(r >> 16);
}
__device__ __forceinline__ float bf16_back(unsigned short h) {
  return __uint_as_float(((unsigned)h) << 16);
}
__device__ __forceinline__ void split8(const float v[8], short8v &hi, short8v &lo) {
  #pragma unroll
  for (int j = 0; j < 8; ++j) {
    unsigned short h = bf16h_rne(v[j]);
    hi[j] = (short)h;
    lo[j] = (short)bf16h_rne(v[j] - bf16_back(h));
  }
}

// ---------------------------------------------------------------- prepA
// Chebyshev solve (I+Q) Z = [I | Jx^T]; 14 blocks x 8 columns each.
#define CHEB_ITERS 14

__global__ __launch_bounds__(256, 1) void prepA_kernel(
    const float* __restrict__ Qg, const float* __restrict__ Ag,
    const float* __restrict__ Gg,
    float* __restrict__ Sg, float* __restrict__ Tg)
{
  __shared__ short sDh[2][16*104], sDl[2][16*104];
  __shared__ float sRed[4];

  const int tid  = threadIdx.x;
  const int w    = tid >> 6, lane = tid & 63;
  const int e    = lane & 15, g = lane >> 4;
  const int row0 = 16*w, rbase = row0 + 4*g;
  const int colg = 8*(int)blockIdx.x + e;   // valid when e<8

  // Gershgorin row sums of M1 = I+Q, wave-0 shfl_xor max reduction
  if (tid < 64) {
    float s = 1.0f;
    #pragma unroll 4
    for (int kq = 0; kq < 16; ++kq) {
      float v[4]; ld4(&Qg[tid*64 + kq*4], v);
      s += fabsf(v[0]) + fabsf(v[1]) + fabsf(v[2]) + fabsf(v[3]);
    }
    #pragma unroll
    for (int off = 32; off >= 1; off >>= 1)
      s = fmaxf(s, __shfl_xor(s, off, 64));
    if (tid == 0) sRed[0] = s;
  }

  // M-frags (A operand): row row0+e of M1, hi/lo splits (register-resident)
  short8v mah[2], mal[2];
  #pragma unroll
  for (int ks = 0; ks < 2; ++ks) {
    const int kb = 32*ks + 8*g;
    float v[8];
    ld4(&Qg[(row0+e)*64 + kb], v);
    ld4(&Qg[(row0+e)*64 + kb + 4], v + 4);
    #pragma unroll
    for (int j = 0; j < 8; ++j)
      if (row0 + e == kb + j) v[j] += 1.0f;
    split8(v, mah[ks], mal[ks]);
  }

  __syncthreads();
  const float B     = sRed[0];
  const float theta = 0.5f*(B + 1.0f);
  const float delta = 0.5f*(B - 1.0f);
  const float sigma = theta / delta;
  float rho = delta / theta;          // 1/sigma

  // rhs b; state x=0, r=b, d=b/theta (registers; lanes e>=8 are zero cols)
  float xv[4] = {0.f,0.f,0.f,0.f}, rv[4], dv[4];
  #pragma unroll
  for (int r = 0; r < 4; ++r) {
    float bb = 0.f;
    if (e < 8) {
      if (colg < 64) {
        bb = (rbase + r == colg) ? 1.0f : 0.0f;
      } else {
        int jr = colg - 64;
        bb = (jr < 16) ? Ag[jr*64 + rbase + r] : Gg[(jr-16)*64 + rbase + r];
      }
    }
    rv[r] = bb;
    dv[r] = bb / theta;
  }
  {
    short4v hv, lv;
    #pragma unroll
    for (int r = 0; r < 4; ++r) {
      unsigned short h = bf16h_rne(dv[r]);
      hv[r] = (short)h;
      lv[r] = (short)bf16h_rne(dv[r] - bf16_back(h));
    }
    *(short4v*)&sDh[0][e*104 + rbase] = hv;
    *(short4v*)&sDl[0][e*104 + rbase] = lv;
  }
  __syncthreads();

  int cur = 0;
  #pragma unroll 1
  for (int it = 0; it < CHEB_ITERS; ++it) {
    // acc = M1 * d  (split-bf16, 6 MFMA)
    float4v acc = {0.f,0.f,0.f,0.f};
    const short* dh = &sDh[cur][0];
    const short* dl = &sDl[cur][0];
    #pragma unroll
    for (int ks = 0; ks < 2; ++ks) {
      int off = e*104 + 32*ks + 8*g;
      short8v bh = *(const short8v*)&dh[off];
      short8v bl = *(const short8v*)&dl[off];
      acc = MFMA_BF16(mah[ks], bh, acc, 0, 0, 0);
      acc = MFMA_BF16(mah[ks], bl, acc, 0, 0, 0);
      acc = MFMA_BF16(mal[ks], bh, acc, 0, 0, 0);
    }
    float rhon = 1.0f / (2.0f*sigma - rho);
    float ca = rhon * rho, cb = 2.0f*rhon/delta;
    short4v hv, lv;
    #pragma unroll
    for (int r = 0; r < 4; ++r) {
      xv[r] += dv[r];
      rv[r] -= acc[r];
      dv[r] = ca*dv[r] + cb*rv[r];
      unsigned short h = bf16h_rne(dv[r]);
      hv[r] = (short)h;
      lv[r] = (short)bf16h_rne(dv[r] - bf16_back(h));
    }
    rho = rhon;
    *(short4v*)&sDh[cur^1][e*104 + rbase] = hv;
    *(short4v*)&sDl[cur^1][e*104 + rbase] = lv;
    __syncthreads();
    cur ^= 1;
  }

  // write out: S columns (symmetric -> store as rows), T columns (scatter)
  if (e < 8) {
    if (colg < 64) {
      *(float4*)&Sg[colg*64 + rbase] = make_float4(xv[0], xv[1], xv[2], xv[3]);
    } else {
      int j = colg - 64;
      #pragma unroll
      for (int r = 0; r < 4; ++r) Tg[(rbase + r)*48 + j] = xv[r];
    }
  }
}

// double-buffered block-GJ step, stride 52 (48x48), threads 0..143
__device__ __forceinline__ void gj_step48(const float* __restrict__ src,
                                          float* __restrict__ dst,
                                          int b, int tid) {
  const bool act = tid < 144;
  const int ig = tid / 12, jg = tid - (tid / 12) * 12;
  float D[4][4], C[4][4], R[4][4], T4[4][4], W[4][4];
  if (act) {
    #pragma unroll
    for (int r = 0; r < 4; ++r) {
      ld4(&src[(4*b + r)*52 + 4*b],  D[r]);
      ld4(&src[(4*ig + r)*52 + 4*b], C[r]);
      ld4(&src[(4*b + r)*52 + 4*jg], R[r]);
      ld4(&src[(4*ig + r)*52 + 4*jg], T4[r]);
    }
    inv4(D);
    if (ig == b) {
      if (jg == b) {
        #pragma unroll
        for (int r = 0; r < 4; ++r)
          #pragma unroll
          for (int q = 0; q < 4; ++q) W[r][q] = D[r][q];
      } else {
        mm4(W, D, R);
      }
    } else {
      float E[4][4];
      mm4(E, C, D);
      if (jg == b) {
        #pragma unroll
        for (int r = 0; r < 4; ++r)
          #pragma unroll
          for (int q = 0; q < 4; ++q) W[r][q] = -E[r][q];
      } else {
        #pragma unroll
        for (int r = 0; r < 4; ++r)
          #pragma unroll
          for (int q = 0; q < 4; ++q) {
            float s = T4[r][q];
            #pragma unroll
            for (int k = 0; k < 4; ++k) s -= E[r][k] * R[k][q];
            W[r][q] = s;
          }
      }
    }
    #pragma unroll
    for (int r = 0; r < 4; ++r) st4(&dst[(4*ig + r)*52 + 4*jg], W[r]);
  }
  __syncthreads();
}

// ---------------------------------------------------------------- prepB
// 1 block: K2 = Jx T + diag(0,I32); GJ48 -> Ki.
__global__ __launch_bounds__(256, 1) void prepB_kernel(
    const float* __restrict__ Ag, const float* __restrict__ Gg,
    const float* __restrict__ Tg, float* __restrict__ Kig)
{
  __shared__ float sT [64*48];   // T (stride 48)
  __shared__ float sK [48*52];   // K2 ping -> Ki
  __shared__ float sJx[48*68];   // Jx staged; later GJ48 pong (48*52)

#define TT_(i,j) sT[(i)*48+(j)]
#define SK_(i,j) sK[(i)*52+(j)]
#define JX_(a,k) sJx[(a)*68+(k)]

  const int tid = threadIdx.x;

  // stage Jx and T
  {
    const float4* A4 = (const float4*)Ag;
    const float4* G4 = (const float4*)Gg;
    {
      int a = tid >> 4, kc = tid & 15;
      float v[4]; ld4((const float*)&A4[tid], v);
      st4(&JX_(a, kc*4), v);
    }
    for (int t = tid; t < 512; t += 256) {
      int a = t >> 4, kc = t & 15;
      float v[4]; ld4((const float*)&G4[t], v);
      st4(&JX_(16 + a, kc*4), v);
    }
    for (int t = tid; t < 768; t += 256) {
      float v[4]; ld4(&Tg[t*4], v); st4(&sT[t*4], v);
    }
  }
  __syncthreads();

  // K2 = Jx T + diag(0,I32)  (192 threads, 3x4 tiles)
  if (tid < 192) {
    int ag = tid / 12, bg = tid - ag*12;
    int a0 = ag*3, b0 = bg*4;
    float acc[3][4] = {};
    #pragma unroll 4
    for (int k = 0; k < 64; ++k) {
      float4 tb = *(const float4*)&TT_(k,b0);
      #pragma unroll
      for (int r = 0; r < 3; ++r) {
        float jv = JX_(a0 + r, k);
        acc[r][0] += jv*tb.x; acc[r][1] += jv*tb.y;
        acc[r][2] += jv*tb.z; acc[r][3] += jv*tb.w;
      }
    }
    #pragma unroll
    for (int r = 0; r < 3; ++r)
      #pragma unroll
      for (int q = 0; q < 4; ++q) {
        int a = a0 + r, b = b0 + q;
        SK_(a,b) = acc[r][q] + ((a == b && a >= 16) ? 1.0f : 0.0f);
      }
  }
  __syncthreads();

  // block-GJ 48 (dbuf; pong overlays dead Jx region) -> Ki in sK
  {
    float* KP = sJx;   // 48*52 = 2496 <= 48*68
    #pragma unroll 1
    for (int p = 0; p < 6; ++p) {
      gj_step48(sK, KP, 2*p,     tid);
      gj_step48(KP, sK, 2*p + 1, tid);
    }
  }

  // write Ki
  #pragma unroll 1
  for (int t = tid; t < 576; t += 256) {
    int k = t / 12, q = t - 12*(t/12);
    float v[4]; ld4(&SK_(k, q*4), v); st4(&Kig[k*48 + q*4], v);
  }
#undef TT_
#undef SK_
#undef JX_
}

// ---------------------------------------------------------------- prep2
__global__ __launch_bounds__(256, 1) void prep2_kernel(
    const float* __restrict__ Sg, const float* __restrict__ Tg,
    const float* __restrict__ Kig,
    float* __restrict__ Pg, float* __restrict__ Bg)
{
  __shared__ float sT [64*48];
  __shared__ float sKi[48*48];
  __shared__ float sR2[48*96];
  __shared__ float sS [24*64];

  const int tid = threadIdx.x;
  const int b   = blockIdx.x;        // rows [24b, 24b+24)
  const int r0b = 24 * b;

  #pragma unroll 1
  for (int t = tid; t < 768; t += 256) {
    float v[4]; ld4(&Tg[t*4], v); st4(&sT[t*4], v);
  }
  #pragma unroll 1
  for (int t = tid; t < 576; t += 256) {
    float v[4]; ld4(&Kig[t*4], v); st4(&sKi[t*4], v);
  }
  #pragma unroll 1
  for (int t = tid; t < 384; t += 256) {
    int ri = t >> 4, q = t & 15;
    if (r0b + ri < 64) {
      float v[4]; ld4(&Sg[(r0b + ri)*64 + q*4], v); st4(&sS[ri*64 + q*4], v);
    }
  }
  __syncthreads();

  #pragma unroll 1
  for (int t = tid; t < 48*64; t += 256) {
    int k = t >> 6, c = t & 63;
    float acc = 0.0f;
    #pragma unroll 4
    for (int m = 0; m < 48; m += 4) {
      float kv[4], tv[4];
      ld4(&sKi[k*48 + m], kv); ld4(&sT[c*48 + m], tv);
      acc += kv[0]*tv[0] + kv[1]*tv[1] + kv[2]*tv[2] + kv[3]*tv[3];
    }
    sR2[k*96 + c] = acc;
  }
  #pragma unroll 1
  for (int t = tid; t < 48*32; t += 256) {
    int k = t >> 5, j = t & 31;
    sR2[k*96 + 64 + j] = sKi[k*48 + 16 + j];
  }
  __syncthreads();

  #pragma unroll 1
  for (int t = tid; t < 24*48; t += 256) {
    int c = r0b + t / 48, k = t - 48*(t/48);
    Bg[c*112 + 64 + k] = sR2[k*96 + c];
  }

  #pragma unroll 1
  for (int task = tid; task < 576; task += 256) {
    int ri = task / 24, jq = task - 24*(task/24);
    int i = r0b + ri, j0 = jq*4;
    if (i < 64) {
      float acc[4];
      #pragma unroll
      for (int q = 0; q < 4; ++q)
        acc[q] = (j0 < 64) ? sS[ri*64 + j0 + q] : 0.0f;
      #pragma unroll 4
      for (int m = 0; m < 48; m += 4) {
        float tv[4], rv[4][4];
        ld4(&sT[i*48 + m], tv);
        ld4(&sR2[(m+0)*96 + j0], rv[0]);
        ld4(&sR2[(m+1)*96 + j0], rv[1]);
        ld4(&sR2[(m+2)*96 + j0], rv[2]);
        ld4(&sR2[(m+3)*96 + j0], rv[3]);
        #pragma unroll
        for (int q = 0; q < 4; ++q)
          #pragma unroll
          for (int s = 0; s < 4; ++s)
            acc[q] -= tv[s] * rv[s][q];
      }
      #pragma unroll
      for (int q = 0; q < 4; ++q) {
        int j = j0 + q;
        Pg[i*96 + j] = acc[q];
        if (j < 64) Bg[i*112 + j] = -acc[q];
      }
    } else {
      int a = i - 64;
      #pragma unroll
      for (int q = 0; q < 4; ++q) {
        int j = j0 + q;
        float v = (i == j ? 1.0f : 0.0f) - sR2[(16 + a)*96 + j];
        Pg[i*96 + j] = v;
        if (j < 64) Bg[i*112 + j] = -v;
      }
    }
  }
}

// ---------------------------------------------------------------- kernel B
#define EB 16   // elements per block; grid = 256 blocks x 384 threads

__global__ __launch_bounds__(384, 1) void iter_kernel(
    const float* __restrict__ xg, const float* __restrict__ pg,
    const float* __restrict__ Pg, const float* __restrict__ Bg,
    float* __restrict__ outg)
{
  // round-18 exact: MFMA split-bf16, xo in registers, x splits in LDS dbuf.
  __shared__ short sXh[2][EB*104], sXl[2][EB*104];

  const int tid   = threadIdx.x;    // 0..383
  const int gbase = blockIdx.x * EB;
  const int w     = tid >> 6;
  const int lane  = tid & 63;
  const int e     = lane & 15;
  const int g     = lane >> 4;
  const int row0  = 16 * w;
  const int rbase = row0 + 4*g;

  short8v pfh[3], pfl[3];
  #pragma unroll
  for (int kc = 0; kc < 3; ++kc) {
    float v[8];
    const float* src = Pg + (row0 + e)*96 + 32*kc + 8*g;
    ld4(src, v); ld4(src + 4, v + 4);
    split8(v, pfh[kc], pfl[kc]);
  }

  float xo[4];
  ld4(xg + (size_t)(gbase + e)*96 + rbase, xo);
  {
    short4v hv, lv;
    #pragma unroll
    for (int r = 0; r < 4; ++r) {
      unsigned short h = bf16h_rne(xo[r]);
      hv[r] = (short)h;
      lv[r] = (short)bf16h_rne(xo[r] - bf16_back(h));
    }
    *(short4v*)&sXh[0][e*104 + rbase] = hv;
    *(short4v*)&sXl[0][e*104 + rbase] = lv;
  }

  float4v cfrag = {0.f, 0.f, 0.f, 0.f};
  #pragma unroll
  for (int kc = 0; kc < 4; ++kc) {
    const int kbase = 32*kc + 8*g;
    float v[8];
    short8v ah, al, bh, bl;
    if (kbase < 112) {
      const float* src = Bg + (row0 + e)*112 + kbase;
      ld4(src, v); ld4(src + 4, v + 4);
    } else {
      #pragma unroll
      for (int j = 0; j < 8; ++j) v[j] = 0.f;
    }
    split8(v, ah, al);
    if (kbase < 112) {
      const float* src = pg + (size_t)(gbase + e)*112 + kbase;
      ld4(src, v); ld4(src + 4, v + 4);
    } else {
      #pragma unroll
      for (int j = 0; j < 8; ++j) v[j] = 0.f;
    }
    split8(v, bh, bl);
    cfrag = MFMA_BF16(ah, bh, cfrag, 0, 0, 0);
    cfrag = MFMA_BF16(ah, bl, cfrag, 0, 0, 0);
    cfrag = MFMA_BF16(al, bh, cfrag, 0, 0, 0);
  }

  __syncthreads();

  const float lob = (row0 < 64) ? -1000.f : 0.f;
  int cur = 0;

  #pragma unroll 1
  for (int it = 0; it < 10; ++it) {
    const short* xhp = &sXh[cur][0];
    const short* xlp = &sXl[cur][0];
    float4v accs0 = cfrag;
    float4v accs1 = {0.f, 0.f, 0.f, 0.f};
    float4v accs2 = {0.f, 0.f, 0.f, 0.f};
    {
      int off = e*104 + 8*g;
      short8v xh0 = *(const short8v*)&xhp[off];
      short8v xl0 = *(const short8v*)&xlp[off];
      short8v xh1 = *(const short8v*)&xhp[off + 32];
      short8v xl1 = *(const short8v*)&xlp[off + 32];
      short8v xh2 = *(const short8v*)&xhp[off + 64];
      short8v xl2 = *(const short8v*)&xlp[off + 64];
      accs0 = MFMA_BF16(pfh[0], xh0, accs0, 0, 0, 0);
      accs1 = MFMA_BF16(pfh[1], xh1, accs1, 0, 0, 0);
      accs2 = MFMA_BF16(pfh[2], xh2, accs2, 0, 0, 0);
      accs0 = MFMA_BF16(pfh[0], xl0, accs0, 0, 0, 0);
      accs1 = MFMA_BF16(pfh[1], xl1, accs1, 0, 0, 0);
      accs2 = MFMA_BF16(pfh[2], xl2, accs2, 0, 0, 0);
      accs0 = MFMA_BF16(pfl[0], xh0, accs0, 0, 0, 0);
      accs1 = MFMA_BF16(pfl[1], xh1, accs1, 0, 0, 0);
      accs2 = MFMA_BF16(pfl[2], xh2, accs2, 0, 0, 0);
    }
    float4v acc = accs0 + accs1 + accs2;

    if (it < 9) {
      short4v hv, lv;
      #pragma unroll
      for (int r = 0; r < 4; ++r) {
        float y = acc[r];
        float z = fminf(fmaxf(2.f*y - xo[r], lob), 1000.f);
        float xn = xo[r] + z - y;
        xo[r] = xn;
        unsigned short h = bf16h_rne(xn);
        hv[r] = (short)h;
        lv[r] = (short)bf16h_rne(xn - bf16_back(h));
      }
      *(short4v*)&sXh[cur ^ 1][e*104 + rbase] = hv;
      *(short4v*)&sXl[cur ^ 1][e*104 + rbase] = lv;
      __syncthreads();
      cur ^= 1;
    } else {
      if (row0 < 64) {
        *(float4*)&outg[(gbase + e)*64 + rbase] =
            make_float4(acc[0], acc[1], acc[2], acc[3]);
      }
    }
  }
}

// ---------------------------------------------------------------- launch
extern "C" void kernel_launch(void* const* d_in, const int* in_sizes, int n_in,
                              void* d_out, int out_size, void* d_ws, size_t ws_size,
                              hipStream_t stream) {
  const float* x     = (const float*)d_in[0];   // (4096, 96)
  const float* parms = (const float*)d_in[1];   // (4096, 112)
  const float* Qg    = (const float*)d_in[2];   // (64, 64)
  const float* Ag    = (const float*)d_in[3];   // (16, 64)
  const float* Gg    = (const float*)d_in[4];   // (32, 64)
  float* out = (float*)d_out;                   // (4096, 64)

  float* ws  = (float*)d_ws;
  float* Pg  = ws;                  // 96*96  = 9216
  float* Bg  = ws + 9216;           // 96*112 = 10752
  float* Sg  = ws + 19968;          // 64*64  = 4096
  float* Tg  = ws + 24064;          // 64*48  = 3072
  float* Kig = ws + 27136;          // 48*48  = 2304

  prepA_kernel<<<14, 256, 0, stream>>>(Qg, Ag, Gg, Sg, Tg);
  prepB_kernel<<<1, 256, 0, stream>>>(Ag, Gg, Tg, Kig);
  prep2_kernel<<<4, 256, 0, stream>>>(Sg, Tg, Kig, Pg, Bg);
  iter_kernel<<<4096 / EB, 384, 0, stream>>>(x, parms, Pg, Bg, out);
}

// Round 24
// 47.024 us; speedup vs baseline: 1.4147x; 1.0225x over previous
//
#include <hip/hip_runtime.h>

// DR splitting solver. BATCH=4096, N=96, M=48. prox_g1 affine: y = P x + Bmat p.
//   S=(I+Q)^{-1}; T=S Jx^T; K2=Jx T+diag(0,I32); R2=K2^{-1}[T^T|E];
//   P=diag(S,I)-[T;E^T]R2; Bmat=[-P[:,:64] | R2^T]
// Iterate 10x: y=Px+c; x += clamp(2y-x,l,u)-y; out=y[:64].
//
// Round-23: 48.1us best (Chebyshev prepA + GJ48 prepB + MFMA iter).
// Round-24: prep2 writes P/Bmat PRE-SPLIT as bf16 hi/lo short arrays (f32
// copies dropped -- iter is the only consumer). iter's prologue loses all
// P/B split VALU (~400 ops/lane) and half its global prologue bytes.
// Numerically identical (same splits of same f32 values).

typedef __attribute__((ext_vector_type(8))) short short8v;
typedef __attribute__((ext_vector_type(4))) short short4v;
typedef __attribute__((ext_vector_type(4))) float float4v;

#define MFMA_BF16 __builtin_amdgcn_mfma_f32_16x16x32_bf16

__device__ __forceinline__ void ld4(const float* p, float* d) {
  float4 v = *(const float4*)p;
  d[0] = v.x; d[1] = v.y; d[2] = v.z; d[3] = v.w;
}
__device__ __forceinline__ void st4(float* p, const float* s) {
  *(float4*)p = make_float4(s[0], s[1], s[2], s[3]);
}
__device__ __forceinline__ float fastrcp(float x) {
  float r = __builtin_amdgcn_rcpf(x);
  return r * (2.0f - x * r);
}
__device__ __forceinline__ void mm4(float W[4][4], const float A[4][4], const float B[4][4]) {
  #pragma unroll
  for (int r = 0; r < 4; ++r)
    #pragma unroll
    for (int q = 0; q < 4; ++q) {
      float s = A[r][0]*B[0][q];
      #pragma unroll
      for (int k = 1; k < 4; ++k) s += A[r][k]*B[k][q];
      W[r][q] = s;
    }
}
__device__ __forceinline__ void inv4(float D[4][4]) {
  #pragma unroll
  for (int p = 0; p < 4; ++p) {
    float pi = fastrcp(D[p][p]);
    D[p][p] = pi;
    #pragma unroll
    for (int q = 0; q < 4; ++q) if (q != p) D[p][q] *= pi;
    #pragma unroll
    for (int i = 0; i < 4; ++i) if (i != p) {
      float f = D[i][p];
      #pragma unroll
      for (int q = 0; q < 4; ++q) if (q != p) D[i][q] -= f * D[p][q];
      D[i][p] = -f * pi;
    }
  }
}
__device__ __forceinline__ unsigned short bf16h_rne(float v) {
  unsigned u = __float_as_uint(v);
  unsigned r = u + 0x7FFFu + ((u >> 16) & 1u);
  return (unsigned short)(r >> 16);
}
__device__ __forceinline__ float bf16_back(unsigned short h) {
  return __uint_as_float(((unsigned)h) << 16);
}
__device__ __forceinline__ void split1(float v, short* ph, short* pl) {
  unsigned short h = bf16h_rne(v);
  *ph = (short)h;
  *pl = (short)bf16h_rne(v - bf16_back(h));
}
__device__ __forceinline__ void split8(const float v[8], short8v &hi, short8v &lo) {
  #pragma unroll
  for (int j = 0; j < 8; ++j) {
    unsigned short h = bf16h_rne(v[j]);
    hi[j] = (short)h;
    lo[j] = (short)bf16h_rne(v[j] - bf16_back(h));
  }
}

// ---------------------------------------------------------------- prepA
// Chebyshev solve (I+Q) Z = [I | Jx^T]; 14 blocks x 8 columns each.
#define CHEB_ITERS 14

__global__ __launch_bounds__(256, 1) void prepA_kernel(
    const float* __restrict__ Qg, const float* __restrict__ Ag,
    const float* __restrict__ Gg,
    float* __restrict__ Sg, float* __restrict__ Tg)
{
  __shared__ short sDh[2][16*104], sDl[2][16*104];
  __shared__ float sRed[4];

  const int tid  = threadIdx.x;
  const int w    = tid >> 6, lane = tid & 63;
  const int e    = lane & 15, g = lane >> 4;
  const int row0 = 16*w, rbase = row0 + 4*g;
  const int colg = 8*(int)blockIdx.x + e;   // valid when e<8

  // Gershgorin row sums of M1 = I+Q, wave-0 shfl_xor max reduction
  if (tid < 64) {
    float s = 1.0f;
    #pragma unroll 4
    for (int kq = 0; kq < 16; ++kq) {
      float v[4]; ld4(&Qg[tid*64 + kq*4], v);
      s += fabsf(v[0]) + fabsf(v[1]) + fabsf(v[2]) + fabsf(v[3]);
    }
    #pragma unroll
    for (int off = 32; off >= 1; off >>= 1)
      s = fmaxf(s, __shfl_xor(s, off, 64));
    if (tid == 0) sRed[0] = s;
  }

  // M-frags (A operand): row row0+e of M1, hi/lo splits (register-resident)
  short8v mah[2], mal[2];
  #pragma unroll
  for (int ks = 0; ks < 2; ++ks) {
    const int kb = 32*ks + 8*g;
    float v[8];
    ld4(&Qg[(row0+e)*64 + kb], v);
    ld4(&Qg[(row0+e)*64 + kb + 4], v + 4);
    #pragma unroll
    for (int j = 0; j < 8; ++j)
      if (row0 + e == kb + j) v[j] += 1.0f;
    split8(v, mah[ks], mal[ks]);
  }

  __syncthreads();
  const float B     = sRed[0];
  const float theta = 0.5f*(B + 1.0f);
  const float delta = 0.5f*(B - 1.0f);
  const float sigma = theta / delta;
  float rho = delta / theta;          // 1/sigma

  // rhs b; state x=0, r=b, d=b/theta (registers; lanes e>=8 are zero cols)
  float xv[4] = {0.f,0.f,0.f,0.f}, rv[4], dv[4];
  #pragma unroll
  for (int r = 0; r < 4; ++r) {
    float bb = 0.f;
    if (e < 8) {
      if (colg < 64) {
        bb = (rbase + r == colg) ? 1.0f : 0.0f;
      } else {
        int jr = colg - 64;
        bb = (jr < 16) ? Ag[jr*64 + rbase + r] : Gg[(jr-16)*64 + rbase + r];
      }
    }
    rv[r] = bb;
    dv[r] = bb / theta;
  }
  {
    short4v hv, lv;
    #pragma unroll
    for (int r = 0; r < 4; ++r) {
      unsigned short h = bf16h_rne(dv[r]);
      hv[r] = (short)h;
      lv[r] = (short)bf16h_rne(dv[r] - bf16_back(h));
    }
    *(short4v*)&sDh[0][e*104 + rbase] = hv;
    *(short4v*)&sDl[0][e*104 + rbase] = lv;
  }
  __syncthreads();

  int cur = 0;
  #pragma unroll 1
  for (int it = 0; it < CHEB_ITERS; ++it) {
    // acc = M1 * d  (split-bf16, 6 MFMA)
    float4v acc = {0.f,0.f,0.f,0.f};
    const short* dh = &sDh[cur][0];
    const short* dl = &sDl[cur][0];
    #pragma unroll
    for (int ks = 0; ks < 2; ++ks) {
      int off = e*104 + 32*ks + 8*g;
      short8v bh = *(const short8v*)&dh[off];
      short8v bl = *(const short8v*)&dl[off];
      acc = MFMA_BF16(mah[ks], bh, acc, 0, 0, 0);
      acc = MFMA_BF16(mah[ks], bl, acc, 0, 0, 0);
      acc = MFMA_BF16(mal[ks], bh, acc, 0, 0, 0);
    }
    float rhon = 1.0f / (2.0f*sigma - rho);
    float ca = rhon * rho, cb = 2.0f*rhon/delta;
    short4v hv, lv;
    #pragma unroll
    for (int r = 0; r < 4; ++r) {
      xv[r] += dv[r];
      rv[r] -= acc[r];
      dv[r] = ca*dv[r] + cb*rv[r];
      unsigned short h = bf16h_rne(dv[r]);
      hv[r] = (short)h;
      lv[r] = (short)bf16h_rne(dv[r] - bf16_back(h));
    }
    rho = rhon;
    *(short4v*)&sDh[cur^1][e*104 + rbase] = hv;
    *(short4v*)&sDl[cur^1][e*104 + rbase] = lv;
    __syncthreads();
    cur ^= 1;
  }

  // write out: S columns (symmetric -> store as rows), T columns (scatter)
  if (e < 8) {
    if (colg < 64) {
      *(float4*)&Sg[colg*64 + rbase] = make_float4(xv[0], xv[1], xv[2], xv[3]);
    } else {
      int j = colg - 64;
      #pragma unroll
      for (int r = 0; r < 4; ++r) Tg[(rbase + r)*48 + j] = xv[r];
    }
  }
}

// double-buffered block-GJ step, stride 52 (48x48), threads 0..143
__device__ __forceinline__ void gj_step48(const float* __restrict__ src,
                                          float* __restrict__ dst,
                                          int b, int tid) {
  const bool act = tid < 144;
  const int ig = tid / 12, jg = tid - (tid / 12) * 12;
  float D[4][4], C[4][4], R[4][4], T4[4][4], W[4][4];
  if (act) {
    #pragma unroll
    for (int r = 0; r < 4; ++r) {
      ld4(&src[(4*b + r)*52 + 4*b],  D[r]);
      ld4(&src[(4*ig + r)*52 + 4*b], C[r]);
      ld4(&src[(4*b + r)*52 + 4*jg], R[r]);
      ld4(&src[(4*ig + r)*52 + 4*jg], T4[r]);
    }
    inv4(D);
    if (ig == b) {
      if (jg == b) {
        #pragma unroll
        for (int r = 0; r < 4; ++r)
          #pragma unroll
          for (int q = 0; q < 4; ++q) W[r][q] = D[r][q];
      } else {
        mm4(W, D, R);
      }
    } else {
      float E[4][4];
      mm4(E, C, D);
      if (jg == b) {
        #pragma unroll
        for (int r = 0; r < 4; ++r)
          #pragma unroll
          for (int q = 0; q < 4; ++q) W[r][q] = -E[r][q];
      } else {
        #pragma unroll
        for (int r = 0; r < 4; ++r)
          #pragma unroll
          for (int q = 0; q < 4; ++q) {
            float s = T4[r][q];
            #pragma unroll
            for (int k = 0; k < 4; ++k) s -= E[r][k] * R[k][q];
            W[r][q] = s;
          }
      }
    }
    #pragma unroll
    for (int r = 0; r < 4; ++r) st4(&dst[(4*ig + r)*52 + 4*jg], W[r]);
  }
  __syncthreads();
}

// ---------------------------------------------------------------- prepB
// 1 block: K2 = Jx T + diag(0,I32); GJ48 -> Ki.
__global__ __launch_bounds__(256, 1) void prepB_kernel(
    const float* __restrict__ Ag, const float* __restrict__ Gg,
    const float* __restrict__ Tg, float* __restrict__ Kig)
{
  __shared__ float sT [64*48];   // T (stride 48)
  __shared__ float sK [48*52];   // K2 ping -> Ki
  __shared__ float sJx[48*68];   // Jx staged; later GJ48 pong (48*52)

#define TT_(i,j) sT[(i)*48+(j)]
#define SK_(i,j) sK[(i)*52+(j)]
#define JX_(a,k) sJx[(a)*68+(k)]

  const int tid = threadIdx.x;

  // stage Jx and T
  {
    const float4* A4 = (const float4*)Ag;
    const float4* G4 = (const float4*)Gg;
    {
      int a = tid >> 4, kc = tid & 15;
      float v[4]; ld4((const float*)&A4[tid], v);
      st4(&JX_(a, kc*4), v);
    }
    for (int t = tid; t < 512; t += 256) {
      int a = t >> 4, kc = t & 15;
      float v[4]; ld4((const float*)&G4[t], v);
      st4(&JX_(16 + a, kc*4), v);
    }
    for (int t = tid; t < 768; t += 256) {
      float v[4]; ld4(&Tg[t*4], v); st4(&sT[t*4], v);
    }
  }
  __syncthreads();

  // K2 = Jx T + diag(0,I32)  (192 threads, 3x4 tiles)
  if (tid < 192) {
    int ag = tid / 12, bg = tid - ag*12;
    int a0 = ag*3, b0 = bg*4;
    float acc[3][4] = {};
    #pragma unroll 4
    for (int k = 0; k < 64; ++k) {
      float4 tb = *(const float4*)&TT_(k,b0);
      #pragma unroll
      for (int r = 0; r < 3; ++r) {
        float jv = JX_(a0 + r, k);
        acc[r][0] += jv*tb.x; acc[r][1] += jv*tb.y;
        acc[r][2] += jv*tb.z; acc[r][3] += jv*tb.w;
      }
    }
    #pragma unroll
    for (int r = 0; r < 3; ++r)
      #pragma unroll
      for (int q = 0; q < 4; ++q) {
        int a = a0 + r, b = b0 + q;
        SK_(a,b) = acc[r][q] + ((a == b && a >= 16) ? 1.0f : 0.0f);
      }
  }
  __syncthreads();

  // block-GJ 48 (dbuf; pong overlays dead Jx region) -> Ki in sK
  {
    float* KP = sJx;   // 48*52 = 2496 <= 48*68
    #pragma unroll 1
    for (int p = 0; p < 6; ++p) {
      gj_step48(sK, KP, 2*p,     tid);
      gj_step48(KP, sK, 2*p + 1, tid);
    }
  }

  // write Ki
  #pragma unroll 1
  for (int t = tid; t < 576; t += 256) {
    int k = t / 12, q = t - 12*(t/12);
    float v[4]; ld4(&SK_(k, q*4), v); st4(&Kig[k*48 + q*4], v);
  }
#undef TT_
#undef SK_
#undef JX_
}

// ---------------------------------------------------------------- prep2
// 4 blocks: R2 in LDS; writes P and Bmat PRE-SPLIT (bf16 hi/lo shorts).
__global__ __launch_bounds__(256, 1) void prep2_kernel(
    const float* __restrict__ Sg, const float* __restrict__ Tg,
    const float* __restrict__ Kig,
    short* __restrict__ Phg, short* __restrict__ Plg,
    short* __restrict__ Bhg, short* __restrict__ Blg)
{
  __shared__ float sT [64*48];
  __shared__ float sKi[48*48];
  __shared__ float sR2[48*96];
  __shared__ float sS [24*64];

  const int tid = threadIdx.x;
  const int b   = blockIdx.x;        // rows [24b, 24b+24)
  const int r0b = 24 * b;

  #pragma unroll 1
  for (int t = tid; t < 768; t += 256) {
    float v[4]; ld4(&Tg[t*4], v); st4(&sT[t*4], v);
  }
  #pragma unroll 1
  for (int t = tid; t < 576; t += 256) {
    float v[4]; ld4(&Kig[t*4], v); st4(&sKi[t*4], v);
  }
  #pragma unroll 1
  for (int t = tid; t < 384; t += 256) {
    int ri = t >> 4, q = t & 15;
    if (r0b + ri < 64) {
      float v[4]; ld4(&Sg[(r0b + ri)*64 + q*4], v); st4(&sS[ri*64 + q*4], v);
    }
  }
  __syncthreads();

  #pragma unroll 1
  for (int t = tid; t < 48*64; t += 256) {
    int k = t >> 6, c = t & 63;
    float acc = 0.0f;
    #pragma unroll 4
    for (int m = 0; m < 48; m += 4) {
      float kv[4], tv[4];
      ld4(&sKi[k*48 + m], kv); ld4(&sT[c*48 + m], tv);
      acc += kv[0]*tv[0] + kv[1]*tv[1] + kv[2]*tv[2] + kv[3]*tv[3];
    }
    sR2[k*96 + c] = acc;
  }
  #pragma unroll 1
  for (int t = tid; t < 48*32; t += 256) {
    int k = t >> 5, j = t & 31;
    sR2[k*96 + 64 + j] = sKi[k*48 + 16 + j];
  }
  __syncthreads();

  // Bmat right slice (split): B[c][64+k] = R2[k][c] for c in [24b, 24b+24)
  #pragma unroll 1
  for (int t = tid; t < 24*48; t += 256) {
    int c = r0b + t / 48, k = t - 48*(t/48);
    float v = sR2[k*96 + c];
    split1(v, &Bhg[c*112 + 64 + k], &Blg[c*112 + 64 + k]);
  }

  // P slice rows [24b, 24b+24): heavy (i<64) or light (i>=64); split writes
  #pragma unroll 1
  for (int task = tid; task < 576; task += 256) {
    int ri = task / 24, jq = task - 24*(task/24);
    int i = r0b + ri, j0 = jq*4;
    if (i < 64) {
      float acc[4];
      #pragma unroll
      for (int q = 0; q < 4; ++q)
        acc[q] = (j0 < 64) ? sS[ri*64 + j0 + q] : 0.0f;
      #pragma unroll 4
      for (int m = 0; m < 48; m += 4) {
        float tv[4], rv[4][4];
        ld4(&sT[i*48 + m], tv);
        ld4(&sR2[(m+0)*96 + j0], rv[0]);
        ld4(&sR2[(m+1)*96 + j0], rv[1]);
        ld4(&sR2[(m+2)*96 + j0], rv[2]);
        ld4(&sR2[(m+3)*96 + j0], rv[3]);
        #pragma unroll
        for (int q = 0; q < 4; ++q)
          #pragma unroll
          for (int s = 0; s < 4; ++s)
            acc[q] -= tv[s] * rv[s][q];
      }
      #pragma unroll
      for (int q = 0; q < 4; ++q) {
        int j = j0 + q;
        split1(acc[q], &Phg[i*96 + j], &Plg[i*96 + j]);
        if (j < 64) split1(-acc[q], &Bhg[i*112 + j], &Blg[i*112 + j]);
      }
    } else {
      int a = i - 64;
      #pragma unroll
      for (int q = 0; q < 4; ++q) {
        int j = j0 + q;
        float v = (i == j ? 1.0f : 0.0f) - sR2[(16 + a)*96 + j];
        split1(v, &Phg[i*96 + j], &Plg[i*96 + j]);
        if (j < 64) split1(-v, &Bhg[i*112 + j], &Blg[i*112 + j]);
      }
    }
  }
}

// ---------------------------------------------------------------- kernel B
#define EB 16   // elements per block; grid = 256 blocks x 384 threads

__global__ __launch_bounds__(384, 1) void iter_kernel(
    const float* __restrict__ xg, const float* __restrict__ pg,
    const short* __restrict__ Phg, const short* __restrict__ Plg,
    const short* __restrict__ Bhg, const short* __restrict__ Blg,
    float* __restrict__ outg)
{
  // MFMA split-bf16; P and Bmat arrive PRE-SPLIT (no prologue split VALU).
  // xo in f32 registers across iterations; x splits in LDS dbuf.
  __shared__ short sXh[2][EB*104], sXl[2][EB*104];

  const int tid   = threadIdx.x;    // 0..383
  const int gbase = blockIdx.x * EB;
  const int w     = tid >> 6;
  const int lane  = tid & 63;
  const int e     = lane & 15;
  const int g     = lane >> 4;
  const int row0  = 16 * w;
  const int rbase = row0 + 4*g;

  // P fragments: direct short8 global loads (pre-split)
  short8v pfh[3], pfl[3];
  #pragma unroll
  for (int kc = 0; kc < 3; ++kc) {
    int off = (row0 + e)*96 + 32*kc + 8*g;
    pfh[kc] = *(const short8v*)&Phg[off];
    pfl[kc] = *(const short8v*)&Plg[off];
  }

  // x state: my 4 values in registers; splits to LDS buffer 0
  float xo[4];
  ld4(xg + (size_t)(gbase + e)*96 + rbase, xo);
  {
    short4v hv, lv;
    #pragma unroll
    for (int r = 0; r < 4; ++r) {
      unsigned short h = bf16h_rne(xo[r]);
      hv[r] = (short)h;
      lv[r] = (short)bf16h_rne(xo[r] - bf16_back(h));
    }
    *(short4v*)&sXh[0][e*104 + rbase] = hv;
    *(short4v*)&sXl[0][e*104 + rbase] = lv;
  }

  // c = Bmat @ parms via MFMA (Bmat pre-split; parms split at runtime)
  float4v cfrag = {0.f, 0.f, 0.f, 0.f};
  const short8v zero8 = {0,0,0,0,0,0,0,0};
  #pragma unroll
  for (int kc = 0; kc < 4; ++kc) {
    const int kbase = 32*kc + 8*g;
    short8v ah, al, bh, bl;
    if (kbase < 112) {
      int off = (row0 + e)*112 + kbase;
      ah = *(const short8v*)&Bhg[off];
      al = *(const short8v*)&Blg[off];
    } else {
      ah = zero8; al = zero8;
    }
    if (kbase < 112) {
      float v[8];
      const float* src = pg + (size_t)(gbase + e)*112 + kbase;
      ld4(src, v); ld4(src + 4, v + 4);
      split8(v, bh, bl);
    } else {
      bh = zero8; bl = zero8;
    }
    cfrag = MFMA_BF16(ah, bh, cfrag, 0, 0, 0);
    cfrag = MFMA_BF16(ah, bl, cfrag, 0, 0, 0);
    cfrag = MFMA_BF16(al, bh, cfrag, 0, 0, 0);
  }

  __syncthreads();   // x splits visible

  const float lob = (row0 < 64) ? -1000.f : 0.f;
  int cur = 0;

  #pragma unroll 1
  for (int it = 0; it < 10; ++it) {
    const short* xhp = &sXh[cur][0];
    const short* xlp = &sXl[cur][0];
    float4v accs0 = cfrag;
    float4v accs1 = {0.f, 0.f, 0.f, 0.f};
    float4v accs2 = {0.f, 0.f, 0.f, 0.f};
    {
      int off = e*104 + 8*g;
      short8v xh0 = *(const short8v*)&xhp[off];
      short8v xl0 = *(const short8v*)&xlp[off];
      short8v xh1 = *(const short8v*)&xhp[off + 32];
      short8v xl1 = *(const short8v*)&xlp[off + 32];
      short8v xh2 = *(const short8v*)&xhp[off + 64];
      short8v xl2 = *(const short8v*)&xlp[off + 64];
      accs0 = MFMA_BF16(pfh[0], xh0, accs0, 0, 0, 0);
      accs1 = MFMA_BF16(pfh[1], xh1, accs1, 0, 0, 0);
      accs2 = MFMA_BF16(pfh[2], xh2, accs2, 0, 0, 0);
      accs0 = MFMA_BF16(pfh[0], xl0, accs0, 0, 0, 0);
      accs1 = MFMA_BF16(pfh[1], xl1, accs1, 0, 0, 0);
      accs2 = MFMA_BF16(pfh[2], xl2, accs2, 0, 0, 0);
      accs0 = MFMA_BF16(pfl[0], xh0, accs0, 0, 0, 0);
      accs1 = MFMA_BF16(pfl[1], xh1, accs1, 0, 0, 0);
      accs2 = MFMA_BF16(pfl[2], xh2, accs2, 0, 0, 0);
    }
    float4v acc = accs0 + accs1 + accs2;

    if (it < 9) {
      short4v hv, lv;
      #pragma unroll
      for (int r = 0; r < 4; ++r) {
        float y = acc[r];
        float z = fminf(fmaxf(2.f*y - xo[r], lob), 1000.f);
        float xn = xo[r] + z - y;
        xo[r] = xn;
        unsigned short h = bf16h_rne(xn);
        hv[r] = (short)h;
        lv[r] = (short)bf16h_rne(xn - bf16_back(h));
      }
      *(short4v*)&sXh[cur ^ 1][e*104 + rbase] = hv;
      *(short4v*)&sXl[cur ^ 1][e*104 + rbase] = lv;
      __syncthreads();
      cur ^= 1;
    } else {
      if (row0 < 64) {
        *(float4*)&outg[(gbase + e)*64 + rbase] =
            make_float4(acc[0], acc[1], acc[2], acc[3]);
      }
    }
  }
}

// ---------------------------------------------------------------- launch
extern "C" void kernel_launch(void* const* d_in, const int* in_sizes, int n_in,
                              void* d_out, int out_size, void* d_ws, size_t ws_size,
                              hipStream_t stream) {
  const float* x     = (const float*)d_in[0];   // (4096, 96)
  const float* parms = (const float*)d_in[1];   // (4096, 112)
  const float* Qg    = (const float*)d_in[2];   // (64, 64)
  const float* Ag    = (const float*)d_in[3];   // (16, 64)
  const float* Gg    = (const float*)d_in[4];   // (32, 64)
  float* out = (float*)d_out;                   // (4096, 64)

  float* ws  = (float*)d_ws;
  float* Sg  = ws;                  // 64*64 = 4096 floats
  float* Tg  = ws + 4096;           // 64*48 = 3072
  float* Kig = ws + 7168;           // 48*48 = 2304  (ends 9472)
  short* Phg = (short*)(ws + 10240);    // 96*96  shorts (16B-aligned)
  short* Plg = Phg + 9216;              // 96*96
  short* Bhg = Phg + 18432;             // 96*112
  short* Blg = Bhg + 10752;             // 96*112 (ends ~120.8 KB total)

  prepA_kernel<<<14, 256, 0, stream>>>(Qg, Ag, Gg, Sg, Tg);
  prepB_kernel<<<1, 256, 0, stream>>>(Ag, Gg, Tg, Kig);
  prep2_kernel<<<4, 256, 0, stream>>>(Sg, Tg, Kig, Phg, Plg, Bhg, Blg);
  iter_kernel<<<4096 / EB, 384, 0, stream>>>(x, parms, Phg, Plg, Bhg, Blg, out);
}